// Round 11
// baseline (451.650 us; speedup 1.0000x reference)
//
#include <hip/hip_runtime.h>

#define S_LEN 2048
#define D_DIM 1024
#define NH    16
#define DHEAD 64

typedef float f32x4 __attribute__((ext_vector_type(4)));
typedef __bf16 bf16x8 __attribute__((ext_vector_type(8)));
typedef unsigned short u16;
typedef unsigned int u32;
typedef unsigned short u16x8 __attribute__((ext_vector_type(8)));
typedef unsigned short u16x4 __attribute__((ext_vector_type(4)));

__device__ __forceinline__ u16 f2bf(float f) {
    union { float f; unsigned u; } c; c.f = f;
    unsigned u = c.u + 0x7fffu + ((c.u >> 16) & 1u);
    return (u16)(u >> 16);
}

// pack two f32 into one u32 of 2 bf16 via v_cvt_pk_bf16_f32.
// NOTE: lo/hi placement swapped vs naming on gfx950 (R8/R9 A/B). Safe ONLY
// where BOTH MFMA operands get the identical within-pair K permutation
// (dot-product invariant) -- i.e. operand pre-packing (k_prep). NOT safe for
// one-sided packs like the P->PV path (R1/R7/R8 failures).
__device__ __forceinline__ u32 cvtpk(float lo, float hi) {
    u32 r;
    asm("v_cvt_pk_bf16_f32 %0, %1, %2" : "=v"(r) : "v"(lo), "v"(hi));
    return r;
}

// pack two f32 into bf16 pair (truncation; bit-exact placement, verified)
__device__ __forceinline__ u32 pack_bf(float lo, float hi) {
    union { float f; u32 u; } a, b; a.f = lo; b.f = hi;
    return (b.u & 0xFFFF0000u) | (a.u >> 16);
}

#if __has_builtin(__builtin_amdgcn_exp2f)
#define EXP2(x) __builtin_amdgcn_exp2f(x)
#else
#define EXP2(x) exp2f(x)
#endif

// 0.25*log2(e), 0.125*log2(e)
#define C_QK  0.36067376022224085f
#define C_SQ  0.18033688011112043f

#define MFMA16(a, b, c) __builtin_amdgcn_mfma_f32_16x16x32_bf16((a), (b), (c), 0, 0, 0)

// ---------------------------------------------------------------------------
// PREP: convert x (4M f32) and Wq (1M f32) to bf16 workspaces.
__global__ __launch_bounds__(256) void k_prep(
    const float* __restrict__ x, const float* __restrict__ Wq,
    u16* __restrict__ xbf, u16* __restrict__ Wqbf) {
    const size_t NX = (size_t)2 * S_LEN * D_DIM / 8;   // 524288 chunks of 8
    const size_t NW = (size_t)D_DIM * D_DIM / 8;       // 131072 chunks
    for (size_t c = (size_t)blockIdx.x * 256 + threadIdx.x; c < NX + NW;
         c += (size_t)gridDim.x * 256) {
        const float* src; u16* dst; size_t off;
        if (c < NX) { src = x;  dst = xbf;  off = c * 8; }
        else        { src = Wq; dst = Wqbf; off = (c - NX) * 8; }
        f32x4 a = *(const f32x4*)(src + off);
        f32x4 b = *(const f32x4*)(src + off + 4);
        union { u32 w[4]; u16x8 v; } o;
        o.w[0] = cvtpk(a[0], a[1]); o.w[1] = cvtpk(a[2], a[3]);
        o.w[2] = cvtpk(b[0], b[1]); o.w[3] = cvtpk(b[2], b[3]);
        *(u16x8*)(dst + off) = o.v;
    }
}

// ---------------------------------------------------------------------------
// MEGA-1: blocks 0..255 = Q projection (128x128, bn = 2-head group), bf16 in
//         blocks 256..383 = Mpart[z][h*64+j][f] partial Wq^T.Wv (8 z-chunks)
__global__ __launch_bounds__(512, 4) void k_mega1(
    const u16* __restrict__ xbf, const u16* __restrict__ Wqbf,
    const float* __restrict__ Wq, const float* __restrict__ Wv,
    const float* __restrict__ bq, const int* __restrict__ mask,
    u16* __restrict__ Qbf, u16* __restrict__ QT,
    float* __restrict__ sq05, float* __restrict__ Mpart) {
    __shared__ __align__(16) char smem[38912];
    const int tid = threadIdx.x;

    if (blockIdx.x >= 256) {
        // ---------------- precomp_M path ----------------
        const int id = blockIdx.x - 256;
        const int z = id & 7, h = id >> 3;
        float* Qp = (float*)smem;              // [64][64]
        float* Vp = (float*)(smem + 16384);    // [64][64]
        const int r = tid >> 3, seg = tid & 7;
        const int j0 = (tid >> 4) * 2;         // 2 j's
        const int f0 = (tid & 15) * 4;         // 4 f's
        f32x4 acc0 = {0.f, 0.f, 0.f, 0.f}, acc1 = acc0;
        for (int c = 0; c < 2; ++c) {
            const int e0 = z * 128 + c * 64;
            __syncthreads();
            const float* q = Wq + (size_t)(e0 + r) * D_DIM + h * DHEAD + seg * 8;
            const float* v = Wv + (size_t)(e0 + r) * D_DIM + h * DHEAD + seg * 8;
            *(f32x4*)&Qp[r * 64 + seg * 8]     = *(const f32x4*)q;
            *(f32x4*)&Qp[r * 64 + seg * 8 + 4] = *(const f32x4*)(q + 4);
            *(f32x4*)&Vp[r * 64 + seg * 8]     = *(const f32x4*)v;
            *(f32x4*)&Vp[r * 64 + seg * 8 + 4] = *(const f32x4*)(v + 4);
            __syncthreads();
#pragma unroll 8
            for (int e = 0; e < 64; ++e) {
                float q0 = Qp[e * 64 + j0], q1 = Qp[e * 64 + j0 + 1];
                f32x4 vv = *(const f32x4*)&Vp[e * 64 + f0];
                acc0 += q0 * vv;
                acc1 += q1 * vv;
            }
        }
        float* dst = Mpart + (size_t)z * 65536 + ((size_t)(h * 64 + j0)) * 64 + f0;
        *(f32x4*)dst        = acc0 * 0.125f;
        *(f32x4*)(dst + 64) = acc1 * 0.125f;
        return;
    }

    // ---------------- qproj path (bf16 staging, oproj pattern) ----------------
    u16* Al = (u16*)smem;              // [128][72]
    u16* Bl = (u16*)(smem + 18432);    // [128][72]
    float* sqp = (float*)(smem + 36864); // [4][128]

    const int lane = tid & 63, w = tid >> 6;
    const int wm = w & 1, wn = w >> 1;          // wn 0..3 (32-col quarters)
    const int col16 = lane & 15, quad = lane >> 4;
    const int bm = blockIdx.x & 31, bn = blockIdx.x >> 5;

    f32x4 acc[4][2];
    const f32x4 z4 = {0.f, 0.f, 0.f, 0.f};
#pragma unroll
    for (int i = 0; i < 4; ++i)
#pragma unroll
        for (int j = 0; j < 2; ++j) acc[i][j] = z4;

    const int ar = tid >> 2, as = tid & 3;
    const u16* pa = xbf + (size_t)(bm * 128 + ar) * D_DIM + as * 16;
    const u16* pb = Wqbf + (size_t)(bn * 128 + ar) * D_DIM + as * 16;

    u16x8 ra[2], rb[2];
#pragma unroll
    for (int i = 0; i < 2; ++i) ra[i] = *(const u16x8*)(pa + i * 8);
#pragma unroll
    for (int i = 0; i < 2; ++i) rb[i] = *(const u16x8*)(pb + i * 8);

    for (int k0 = 0; k0 < D_DIM; k0 += 64) {
        __syncthreads();
#pragma unroll
        for (int i = 0; i < 2; ++i) *(u16x8*)&Al[ar * 72 + as * 16 + i * 8] = ra[i];
#pragma unroll
        for (int i = 0; i < 2; ++i) *(u16x8*)&Bl[ar * 72 + as * 16 + i * 8] = rb[i];
        __syncthreads();
        if (k0 + 64 < D_DIM) {
#pragma unroll
            for (int i = 0; i < 2; ++i) ra[i] = *(const u16x8*)(pa + k0 + 64 + i * 8);
#pragma unroll
            for (int i = 0; i < 2; ++i) rb[i] = *(const u16x8*)(pb + k0 + 64 + i * 8);
        }
#pragma unroll
        for (int kh = 0; kh < 2; ++kh) {
            bf16x8 af[4];
#pragma unroll
            for (int mt = 0; mt < 4; ++mt)
                af[mt] = *(const bf16x8*)&Al[(wm * 64 + mt * 16 + col16) * 72 + kh * 32 + quad * 8];
#pragma unroll
            for (int nt = 0; nt < 2; ++nt) {
                bf16x8 bfr = *(const bf16x8*)&Bl[(wn * 32 + nt * 16 + col16) * 72 + kh * 32 + quad * 8];
#pragma unroll
                for (int mt = 0; mt < 4; ++mt)
                    acc[mt][nt] = MFMA16(af[mt], bfr, acc[mt][nt]);
            }
        }
    }

    // epilogue: bias, Qbf store, ||q||^2 partials, LDS transpose for QT
    const int hh = wn >> 1;                     // head half within tile
    f32x4 ssum[4];
#pragma unroll
    for (int mt = 0; mt < 4; ++mt) ssum[mt] = z4;

    u16 qv16[2][4][4];
#pragma unroll
    for (int nt = 0; nt < 2; ++nt) {
        int col = bn * 128 + wn * 32 + nt * 16 + col16;
        float bqv = bq[col];
#pragma unroll
        for (int mt = 0; mt < 4; ++mt) {
            int row0 = bm * 128 + wm * 64 + mt * 16 + quad * 4;
#pragma unroll
            for (int rr = 0; rr < 4; ++rr) {
                float qv = acc[mt][nt][rr] + bqv;
                ssum[mt][rr] += qv * qv;
                u16 bv = f2bf(qv);
                qv16[nt][mt][rr] = bv;
                Qbf[(size_t)(row0 + rr) * D_DIM + col] = bv;
            }
        }
    }
    float vred[4][4];
#pragma unroll
    for (int mt = 0; mt < 4; ++mt)
#pragma unroll
        for (int rr = 0; rr < 4; ++rr) {
            float v = ssum[mt][rr];
            v += __shfl_xor(v, 1); v += __shfl_xor(v, 2);
            v += __shfl_xor(v, 4); v += __shfl_xor(v, 8);
            vred[mt][rr] = v;
        }
    if (col16 == 0) {
#pragma unroll
        for (int mt = 0; mt < 4; ++mt)
#pragma unroll
            for (int rr = 0; rr < 4; ++rr)
                sqp[wn * 128 + wm * 64 + mt * 16 + quad * 4 + rr] = vred[mt][rr];
    }
    __syncthreads();   // MFMA frag reads done; Al/Bl reusable; sqp visible

    // transpose: Td[head][d][s_local], stride 130 u16
    u16* Td = (u16*)smem;
#pragma unroll
    for (int nt = 0; nt < 2; ++nt) {
        int dloc = (wn & 1) * 32 + nt * 16 + col16;
#pragma unroll
        for (int mt = 0; mt < 4; ++mt) {
            int sl = wm * 64 + mt * 16 + quad * 4;
#pragma unroll
            for (int rr = 0; rr < 4; ++rr)
                Td[(hh * 64 + dloc) * 130 + sl + rr] = qv16[nt][mt][rr];
        }
    }
    __syncthreads();

    const int bb = (bm * 128) >> 11, s0 = (bm * 128) & 2047;
    if (tid < 256) {
        int r = tid & 127, hh2 = tid >> 7;
        float v = sqp[(2 * hh2) * 128 + r] + sqp[(2 * hh2 + 1) * 128 + r];
        int sidx = s0 + r;
        float o = mask[bb * S_LEN + sidx] ? v * C_SQ : 1e30f;
        sq05[((size_t)(bb * NH + bn * 2 + hh2)) * S_LEN + sidx] = o;
    }
    {
        int dr = tid >> 2, ch = tid & 3;
        int hh3 = dr >> 6, d = dr & 63;
        u16* dst = QT + ((size_t)(bb * NH + bn * 2 + hh3) * DHEAD + d) * S_LEN + s0 + ch * 32;
        const u16* src = Td + (hh3 * 64 + d) * 130 + ch * 32;
#pragma unroll
        for (int i = 0; i < 4; ++i)
            *(u16x8*)(dst + i * 8) = *(const u16x8*)(src + i * 8);
    }
}

// ---------------------------------------------------------------------------
// MEGA-2: blocks 0..511 = fused L2 attention (8 waves: wq x wk 4-way keys)
//         blocks 512..767 = W2[o,c] = (sum_z Mpart) · Wout fold
__global__ __launch_bounds__(512, 4) void k_mega2(
    const u16* __restrict__ Qbf, const u16* __restrict__ QT,
    const float* __restrict__ sq05, u16* __restrict__ attnO,
    const float* __restrict__ Mpart, const float* __restrict__ Wout,
    u16* __restrict__ W2) {
    __shared__ __align__(16) char smem[34816];
    const int tid = threadIdx.x;

    if (blockIdx.x >= 512) {
        // ---------------- precomp_W2 path (512-thread version) ----------------
        const int id = blockIdx.x - 512;
        const int ob = id & 15, h = id >> 4;
        float* Ms = (float*)smem;              // [64][65]
        float* Ws = (float*)(smem + 16640);    // [64][65]
        {
            int rr = tid >> 3, seg = tid & 7;
            const size_t mo = ((size_t)(h * 64 + rr)) * 64 + seg * 8;
            const float* ws = Wout + (size_t)(ob * 64 + rr) * D_DIM + h * DHEAD + seg * 8;
#pragma unroll
            for (int e = 0; e < 8; ++e) {
                float s = 0.f;
#pragma unroll
                for (int k = 0; k < 8; ++k) s += Mpart[mo + e + (size_t)k * 65536];
                Ms[rr * 65 + seg * 8 + e] = s;
                Ws[rr * 65 + seg * 8 + e] = ws[e];
            }
        }
        __syncthreads();
        int j = tid & 63, o0 = (tid >> 6) * 8;
        for (int oo = o0; oo < o0 + 8; ++oo) {
            float acc = 0.f;
#pragma unroll
            for (int f = 0; f < 64; ++f) acc += Ms[j * 65 + f] * Ws[oo * 65 + f];
            W2[(size_t)(ob * 64 + oo) * D_DIM + h * DHEAD + j] = f2bf(acc);
        }
        return;
    }

    // ---------------- flash path: 8 waves ----------------
    u16* Kt  = (u16*)smem;              // [128][64] u16, xor-swizzled cols
    u16* KtT = (u16*)(smem + 16384);    // [64][128] u16, xor-swizzled cols
    float* sql = (float*)(smem + 32768);// [128]

    const int lane = tid & 63, w = tid >> 6;
    const int col16 = lane & 15, quad = lane >> 4;
    const int wq = w & 1, wk = w >> 1;   // wq 0..1 (q halves), wk 0..3 (key quarters)
    const int bh = blockIdx.x & 31;      // (b,h) in low bits -> same XCD
    const int qt = blockIdx.x >> 5;
    const int h = bh & 15;
    const int b = bh >> 4;
    const u16* qbase = Qbf + (size_t)b * S_LEN * D_DIM + h * DHEAD;
    const u16* qtbase = QT + ((size_t)(b * NH + h)) * DHEAD * S_LEN;
    const float* sqb = sq05 + ((size_t)(b * NH + h)) * S_LEN;

    // loop-invariant Q^T B-fragments (global, once)
    bf16x8 qb[4][2];
#pragma unroll
    for (int nq = 0; nq < 4; ++nq)
#pragma unroll
        for (int k0 = 0; k0 < 2; ++k0)
            qb[nq][k0] = *(const bf16x8*)(qbase +
                (size_t)(qt * 128 + wq * 64 + nq * 16 + col16) * D_DIM + k0 * 32 + quad * 8);

    // Kt read offsets: wave's 32-key slice = rows [wk*32, wk*32+32)
    const int r00 = wk * 32 + (col16 >> 2) * 8 + (col16 & 3);
    const int swzA = (col16 & 3) | (((col16 >> 2) & 1) << 2);
    const int krow00 = r00 * 64 + (quad ^ swzA) * 8;
    const int sq00 = wk * 32 + quad * 8;
    int vrow[4];
#pragma unroll
    for (int dblk = 0; dblk < 4; ++dblk) {
        int rT = dblk * 16 + col16;
        vrow[dblk] = rT * 128 + ((wk * 4 + quad) ^ (rT & 7)) * 8;
    }

    // staging assignments (512 threads: 2 chunks each)
    const int kr = tid >> 2, ks = tid & 3;
    const int td = tid >> 3, ts = tid & 7;
    const int kswz = (kr & 3) | (((kr >> 3) & 1) << 2);
    const int tswz = td & 7;
    const u16* ksrc = qbase + (size_t)kr * D_DIM + ks * 16;
    const u16* tsrc = qtbase + (size_t)td * S_LEN + ts * 16;

    u16x8 pk[2], pt[2];
    float sv = 0.f;
#pragma unroll
    for (int i = 0; i < 2; ++i) pk[i] = *(const u16x8*)(ksrc + i * 8);
#pragma unroll
    for (int i = 0; i < 2; ++i) pt[i] = *(const u16x8*)(tsrc + i * 8);
    if (tid < 128) sv = sqb[tid];

    f32x4 Oacc[4][4], lacc[4];
    const f32x4 z4 = {0.f, 0.f, 0.f, 0.f};
#pragma unroll
    for (int n = 0; n < 4; ++n) {
        lacc[n] = z4;
#pragma unroll
        for (int d = 0; d < 4; ++d) Oacc[d][n] = z4;
    }
    bf16x8 ones;
    {
        union { u16x8 u; bf16x8 b; } cv;
#pragma unroll
        for (int e = 0; e < 8; ++e) cv.u[e] = 0x3F80;
        ones = cv.b;
    }

    for (int j = 0; j < S_LEN / 128; ++j) {
        __syncthreads();
#pragma unroll
        for (int i = 0; i < 2; ++i)
            *(u16x8*)(Kt + kr * 64 + ((ks * 2 + i) ^ kswz) * 8) = pk[i];
#pragma unroll
        for (int i = 0; i < 2; ++i)
            *(u16x8*)(KtT + td * 128 + ((ts * 2 + i) ^ tswz) * 8) = pt[i];
        if (tid < 128) sql[tid] = sv;
        __syncthreads();

        int jn = (j + 1) & 15;
        {
            const u16* kn = ksrc + (size_t)jn * 128 * D_DIM;
            const u16* tn = tsrc + (size_t)jn * 128;
#pragma unroll
            for (int i = 0; i < 2; ++i) pk[i] = *(const u16x8*)(kn + i * 8);
#pragma unroll
            for (int i = 0; i < 2; ++i) pt[i] = *(const u16x8*)(tn + i * 8);
            if (tid < 128) sv = sqb[jn * 128 + tid];
        }

        // S^T (32 keys x 64 q) for this wave's key quarter
        f32x4 sacc[2][4];
#pragma unroll
        for (int kbh = 0; kbh < 2; ++kbh)
#pragma unroll
            for (int nq = 0; nq < 4; ++nq) sacc[kbh][nq] = z4;
#pragma unroll
        for (int kbh = 0; kbh < 2; ++kbh) {
            int kro = krow00 + kbh * 256;
            bf16x8 a0 = *(const bf16x8*)(Kt + kro);
            bf16x8 a1 = *(const bf16x8*)(Kt + (kro ^ 32));
#pragma unroll
            for (int nq = 0; nq < 4; ++nq) {
                sacc[kbh][nq] = MFMA16(a0, qb[nq][0], sacc[kbh][nq]);
                sacc[kbh][nq] = MFMA16(a1, qb[nq][1], sacc[kbh][nq]);
            }
        }

        // hoist V-fragment LDS reads: latency hides under the exp chain
        bf16x8 va[4];
#pragma unroll
        for (int dblk = 0; dblk < 4; ++dblk)
            va[dblk] = *(const bf16x8*)(KtT + vrow[dblk]);

        u32 pf[4][4];
#pragma unroll
        for (int kbh = 0; kbh < 2; ++kbh) {
            f32x4 sqv = *(const f32x4*)(sql + sq00 + kbh * 4);
#pragma unroll
            for (int nq = 0; nq < 4; ++nq) {
                float p0 = EXP2(fmaf(sacc[kbh][nq][0], C_QK, -sqv[0]));
                float p1 = EXP2(fmaf(sacc[kbh][nq][1], C_QK, -sqv[1]));
                float p2 = EXP2(fmaf(sacc[kbh][nq][2], C_QK, -sqv[2]));
                float p3 = EXP2(fmaf(sacc[kbh][nq][3], C_QK, -sqv[3]));
                pf[nq][kbh * 2]     = pack_bf(p0, p1);
                pf[nq][kbh * 2 + 1] = pack_bf(p2, p3);
            }
        }

#pragma unroll
        for (int nq = 0; nq < 4; ++nq) {
            union { u32 u[4]; bf16x8 b; } pb;
#pragma unroll
            for (int i = 0; i < 4; ++i) pb.u[i] = pf[nq][i];
            lacc[nq] = MFMA16(ones, pb.b, lacc[nq]);   // key-sums, rows replicated
#pragma unroll
            for (int dblk = 0; dblk < 4; ++dblk)
                Oacc[dblk][nq] = MFMA16(va[dblk], pb.b, Oacc[dblk][nq]);
        }
    }

    // cross-wave (4-way key-quarter) combine + epilogue, chunked per dblk
    __syncthreads();
    float* Obuf = (float*)smem;                 // [3][2][4][64] f32x4 = 24576 B
    float* lred = (float*)(smem + 24576);       // [3][2][4][64] f32   =  6144 B
    if (wk) {
#pragma unroll
        for (int nq = 0; nq < 4; ++nq)
            lred[(((wk - 1) * 2 + wq) * 4 + nq) * 64 + lane] = lacc[nq][0];
    }
    float rinv[4];
    u16* obase = attnO + (size_t)b * S_LEN * D_DIM + h * DHEAD;
    for (int dblk = 0; dblk < 4; ++dblk) {
        if (wk) {
#pragma unroll
            for (int nq = 0; nq < 4; ++nq)
                *(f32x4*)(Obuf + ((((wk - 1) * 2 + wq) * 4 + nq) * 64 + lane) * 4) = Oacc[dblk][nq];
        }
        __syncthreads();
        if (!wk) {
            if (dblk == 0) {
#pragma unroll
                for (int nq = 0; nq < 4; ++nq)
                    rinv[nq] = 1.f / (lacc[nq][0]
                        + lred[((0 * 2 + wq) * 4 + nq) * 64 + lane]
                        + lred[((1 * 2 + wq) * 4 + nq) * 64 + lane]
                        + lred[((2 * 2 + wq) * 4 + nq) * 64 + lane]);
            }
#pragma unroll
            for (int nq = 0; nq < 4; ++nq) {
                f32x4 o = Oacc[dblk][nq];
#pragma unroll
                for (int m = 0; m < 3; ++m)
                    o += *(const f32x4*)(Obuf + (((m * 2 + wq) * 4 + nq) * 64 + lane) * 4);
                int q = qt * 128 + wq * 64 + nq * 16 + col16;
                u16x4 pkk;
#pragma unroll
                for (int rr = 0; rr < 4; ++rr) pkk[rr] = f2bf(o[rr] * rinv[nq]);
                *(u16x4*)(obase + (size_t)q * D_DIM + dblk * 16 + quad * 4) = pkk;
            }
        }
        __syncthreads();
    }
}

// ---------------------------------------------------------------------------
// Output GEMM, 64x128 tile, 256 threads, grid (64,8) = 512 blocks (2/CU):
// out[s,o] = x[s,o] + bout[o] + attnO·W2^T
__global__ __launch_bounds__(256, 4) void k_oproj(
    const u16* __restrict__ attnO, const u16* __restrict__ W2,
    const float* __restrict__ x, const float* __restrict__ bout, float* __restrict__ out) {
    __shared__ __align__(16) char smem[27648];
    u16* Al = (u16*)smem;              // [64][72]
    u16* Bl = (u16*)(smem + 9216);     // [128][72]
    const int tid = threadIdx.x, lane = tid & 63, wn = tid >> 6;  // wn 0..3
    const int col16 = lane & 15, quad = lane >> 4;
    const int bm = blockIdx.x, bn = blockIdx.y;

    f32x4 acc[4][2];
    const f32x4 z4 = {0.f, 0.f, 0.f, 0.f};
#pragma unroll
    for (int i = 0; i < 4; ++i)
#pragma unroll
        for (int j = 0; j < 2; ++j) acc[i][j] = z4;

    // staging: A 64 rows x 64 cols (4 thr/row, 16 cols each);
    //          B 128 rows x 64 cols (2 thr/row, 32 cols each)
    const int arA = tid >> 2, asA = tid & 3;
    const int brB = tid >> 1, bsB = tid & 1;
    const u16* pa = attnO + (size_t)(bm * 64 + arA) * D_DIM + asA * 16;
    const u16* pb = W2 + (size_t)(bn * 128 + brB) * D_DIM + bsB * 32;

    u16x8 ra[2], rb[4];
#pragma unroll
    for (int i = 0; i < 2; ++i) ra[i] = *(const u16x8*)(pa + i * 8);
#pragma unroll
    for (int i = 0; i < 4; ++i) rb[i] = *(const u16x8*)(pb + i * 8);

    for (int k0 = 0; k0 < D_DIM; k0 += 64) {
        __syncthreads();
#pragma unroll
        for (int i = 0; i < 2; ++i) *(u16x8*)&Al[arA * 72 + asA * 16 + i * 8] = ra[i];
#pragma unroll
        for (int i = 0; i < 4; ++i) *(u16x8*)&Bl[brB * 72 + bsB * 32 + i * 8] = rb[i];
        __syncthreads();
        if (k0 + 64 < D_DIM) {
#pragma unroll
            for (int i = 0; i < 2; ++i) ra[i] = *(const u16x8*)(pa + k0 + 64 + i * 8);
#pragma unroll
            for (int i = 0; i < 4; ++i) rb[i] = *(const u16x8*)(pb + k0 + 64 + i * 8);
        }
#pragma unroll
        for (int kh = 0; kh < 2; ++kh) {
            bf16x8 af[4];
#pragma unroll
            for (int mt = 0; mt < 4; ++mt)
                af[mt] = *(const bf16x8*)&Al[(mt * 16 + col16) * 72 + kh * 32 + quad * 8];
#pragma unroll
            for (int nt = 0; nt < 2; ++nt) {
                bf16x8 bfr = *(const bf16x8*)&Bl[(wn * 32 + nt * 16 + col16) * 72 + kh * 32 + quad * 8];
#pragma unroll
                for (int mt = 0; mt < 4; ++mt)
                    acc[mt][nt] = MFMA16(af[mt], bfr, acc[mt][nt]);
            }
        }
    }
#pragma unroll
    for (int nt = 0; nt < 2; ++nt) {
        int col = bn * 128 + wn * 32 + nt * 16 + col16;
        float bv = bout[col];
#pragma unroll
        for (int mt = 0; mt < 4; ++mt) {
            int row0 = bm * 64 + mt * 16 + quad * 4;
#pragma unroll
            for (int rr = 0; rr < 4; ++rr) {
                size_t idx = (size_t)(row0 + rr) * D_DIM + col;
                out[idx] = acc[mt][nt][rr] + x[idx] + bv;
            }
        }
    }
}

// ---------------------------------------------------------------------------
extern "C" void kernel_launch(void* const* d_in, const int* in_sizes, int n_in,
                              void* d_out, int out_size, void* d_ws, size_t ws_size,
                              hipStream_t stream) {
    const float* x    = (const float*)d_in[0];
    const float* Wq   = (const float*)d_in[1];
    const float* bq   = (const float*)d_in[2];
    const float* Wv   = (const float*)d_in[3];
    const float* Wout = (const float*)d_in[4];
    const float* bout = (const float*)d_in[5];
    const int*   mask = (const int*)d_in[6];
    float* out = (float*)d_out;

    char* ws = (char*)d_ws;
    u16*   Qbf   = (u16*)(ws);                         // 8 MB
    u16*   QT    = (u16*)(ws + (8u << 20));            // 8 MB
    u16*   attnO = (u16*)(ws + (16u << 20));           // 8 MB (aliases xbf)
    u16*   W2    = (u16*)(ws + (24u << 20));           // 2 MB (aliases Wqbf)
    float* Mpart = (float*)(ws + (26u << 20));         // 2 MB (8 partials)
    float* sq05  = (float*)(ws + (28u << 20));         // 256 KB
    // bf16 operand staging: stream-ordered aliases (read before overwrite)
    u16*   xbf   = attnO;   // written by k_prep, read by k_mega1, then attnO
    u16*   Wqbf  = W2;      // written by k_prep, read by k_mega1, then W2

    k_prep<<<dim3(2048), dim3(256), 0, stream>>>(x, Wq, xbf, Wqbf);
    k_mega1<<<dim3(384), dim3(512), 0, stream>>>(xbf, Wqbf, Wq, Wv, bq, mask, Qbf, QT, sq05, Mpart);
    k_mega2<<<dim3(768), dim3(512), 0, stream>>>(Qbf, QT, sq05, attnO, Mpart, Wout, W2);
    k_oproj<<<dim3(64, 8), dim3(256), 0, stream>>>(attnO, W2, x, bout, out);
}

// Round 12
// 194.272 us; speedup vs baseline: 2.3248x; 2.3248x over previous
//
#include <hip/hip_runtime.h>

#define S_LEN 2048
#define D_DIM 1024
#define NH    16
#define DHEAD 64

typedef float f32x4 __attribute__((ext_vector_type(4)));
typedef __bf16 bf16x8 __attribute__((ext_vector_type(8)));
typedef unsigned short u16;
typedef unsigned int u32;
typedef unsigned short u16x8 __attribute__((ext_vector_type(8)));
typedef unsigned short u16x4 __attribute__((ext_vector_type(4)));

__device__ __forceinline__ u16 f2bf(float f) {
    union { float f; unsigned u; } c; c.f = f;
    unsigned u = c.u + 0x7fffu + ((c.u >> 16) & 1u);
    return (u16)(u >> 16);
}

// pack two f32 into one u32 of 2 bf16 via v_cvt_pk_bf16_f32.
// NOTE: lo/hi placement swapped vs naming on gfx950 (R8/R9 A/B). Safe ONLY
// where BOTH MFMA operands get the identical within-pair K permutation
// (dot-product invariant) -- i.e. operand pre-packing (k_prep). NOT safe for
// one-sided packs like the P->PV path (R1/R7/R8 failures).
__device__ __forceinline__ u32 cvtpk(float lo, float hi) {
    u32 r;
    asm("v_cvt_pk_bf16_f32 %0, %1, %2" : "=v"(r) : "v"(lo), "v"(hi));
    return r;
}

// pack two f32 into bf16 pair (truncation; bit-exact placement, verified)
__device__ __forceinline__ u32 pack_bf(float lo, float hi) {
    union { float f; u32 u; } a, b; a.f = lo; b.f = hi;
    return (b.u & 0xFFFF0000u) | (a.u >> 16);
}

#if __has_builtin(__builtin_amdgcn_exp2f)
#define EXP2(x) __builtin_amdgcn_exp2f(x)
#else
#define EXP2(x) exp2f(x)
#endif

// 0.25*log2(e), 0.125*log2(e)
#define C_QK  0.36067376022224085f
#define C_SQ  0.18033688011112043f

#define MFMA16(a, b, c) __builtin_amdgcn_mfma_f32_16x16x32_bf16((a), (b), (c), 0, 0, 0)

// ---------------------------------------------------------------------------
// PREP: convert x (4M f32) and Wq (1M f32) to bf16 workspaces.
__global__ __launch_bounds__(256) void k_prep(
    const float* __restrict__ x, const float* __restrict__ Wq,
    u16* __restrict__ xbf, u16* __restrict__ Wqbf) {
    const size_t NX = (size_t)2 * S_LEN * D_DIM / 8;   // 524288 chunks of 8
    const size_t NW = (size_t)D_DIM * D_DIM / 8;       // 131072 chunks
    for (size_t c = (size_t)blockIdx.x * 256 + threadIdx.x; c < NX + NW;
         c += (size_t)gridDim.x * 256) {
        const float* src; u16* dst; size_t off;
        if (c < NX) { src = x;  dst = xbf;  off = c * 8; }
        else        { src = Wq; dst = Wqbf; off = (c - NX) * 8; }
        f32x4 a = *(const f32x4*)(src + off);
        f32x4 b = *(const f32x4*)(src + off + 4);
        union { u32 w[4]; u16x8 v; } o;
        o.w[0] = cvtpk(a[0], a[1]); o.w[1] = cvtpk(a[2], a[3]);
        o.w[2] = cvtpk(b[0], b[1]); o.w[3] = cvtpk(b[2], b[3]);
        *(u16x8*)(dst + off) = o.v;
    }
}

// ---------------------------------------------------------------------------
// MEGA-1: blocks 0..255 = Q projection (128x128, bn = 2-head group), bf16 in
//         blocks 256..383 = Mpart[z][h*64+j][f] partial Wq^T.Wv (8 z-chunks)
__global__ __launch_bounds__(512, 4) void k_mega1(
    const u16* __restrict__ xbf, const u16* __restrict__ Wqbf,
    const float* __restrict__ Wq, const float* __restrict__ Wv,
    const float* __restrict__ bq, const int* __restrict__ mask,
    u16* __restrict__ Qbf, u16* __restrict__ QT,
    float* __restrict__ sq05, float* __restrict__ Mpart) {
    __shared__ __align__(16) char smem[38912];
    const int tid = threadIdx.x;

    if (blockIdx.x >= 256) {
        // ---------------- precomp_M path ----------------
        const int id = blockIdx.x - 256;
        const int z = id & 7, h = id >> 3;
        float* Qp = (float*)smem;              // [64][64]
        float* Vp = (float*)(smem + 16384);    // [64][64]
        const int r = tid >> 3, seg = tid & 7;
        const int j0 = (tid >> 4) * 2;         // 2 j's
        const int f0 = (tid & 15) * 4;         // 4 f's
        f32x4 acc0 = {0.f, 0.f, 0.f, 0.f}, acc1 = acc0;
        for (int c = 0; c < 2; ++c) {
            const int e0 = z * 128 + c * 64;
            __syncthreads();
            const float* q = Wq + (size_t)(e0 + r) * D_DIM + h * DHEAD + seg * 8;
            const float* v = Wv + (size_t)(e0 + r) * D_DIM + h * DHEAD + seg * 8;
            *(f32x4*)&Qp[r * 64 + seg * 8]     = *(const f32x4*)q;
            *(f32x4*)&Qp[r * 64 + seg * 8 + 4] = *(const f32x4*)(q + 4);
            *(f32x4*)&Vp[r * 64 + seg * 8]     = *(const f32x4*)v;
            *(f32x4*)&Vp[r * 64 + seg * 8 + 4] = *(const f32x4*)(v + 4);
            __syncthreads();
#pragma unroll 8
            for (int e = 0; e < 64; ++e) {
                float q0 = Qp[e * 64 + j0], q1 = Qp[e * 64 + j0 + 1];
                f32x4 vv = *(const f32x4*)&Vp[e * 64 + f0];
                acc0 += q0 * vv;
                acc1 += q1 * vv;
            }
        }
        float* dst = Mpart + (size_t)z * 65536 + ((size_t)(h * 64 + j0)) * 64 + f0;
        *(f32x4*)dst        = acc0 * 0.125f;
        *(f32x4*)(dst + 64) = acc1 * 0.125f;
        return;
    }

    // ---------------- qproj path (bf16 staging, oproj pattern) ----------------
    u16* Al = (u16*)smem;              // [128][72]
    u16* Bl = (u16*)(smem + 18432);    // [128][72]
    float* sqp = (float*)(smem + 36864); // [4][128]

    const int lane = tid & 63, w = tid >> 6;
    const int wm = w & 1, wn = w >> 1;          // wn 0..3 (32-col quarters)
    const int col16 = lane & 15, quad = lane >> 4;
    const int bm = blockIdx.x & 31, bn = blockIdx.x >> 5;

    f32x4 acc[4][2];
    const f32x4 z4 = {0.f, 0.f, 0.f, 0.f};
#pragma unroll
    for (int i = 0; i < 4; ++i)
#pragma unroll
        for (int j = 0; j < 2; ++j) acc[i][j] = z4;

    const int ar = tid >> 2, as = tid & 3;
    const u16* pa = xbf + (size_t)(bm * 128 + ar) * D_DIM + as * 16;
    const u16* pb = Wqbf + (size_t)(bn * 128 + ar) * D_DIM + as * 16;

    u16x8 ra[2], rb[2];
#pragma unroll
    for (int i = 0; i < 2; ++i) ra[i] = *(const u16x8*)(pa + i * 8);
#pragma unroll
    for (int i = 0; i < 2; ++i) rb[i] = *(const u16x8*)(pb + i * 8);

    for (int k0 = 0; k0 < D_DIM; k0 += 64) {
        __syncthreads();
#pragma unroll
        for (int i = 0; i < 2; ++i) *(u16x8*)&Al[ar * 72 + as * 16 + i * 8] = ra[i];
#pragma unroll
        for (int i = 0; i < 2; ++i) *(u16x8*)&Bl[ar * 72 + as * 16 + i * 8] = rb[i];
        __syncthreads();
        if (k0 + 64 < D_DIM) {
#pragma unroll
            for (int i = 0; i < 2; ++i) ra[i] = *(const u16x8*)(pa + k0 + 64 + i * 8);
#pragma unroll
            for (int i = 0; i < 2; ++i) rb[i] = *(const u16x8*)(pb + k0 + 64 + i * 8);
        }
#pragma unroll
        for (int kh = 0; kh < 2; ++kh) {
            bf16x8 af[4];
#pragma unroll
            for (int mt = 0; mt < 4; ++mt)
                af[mt] = *(const bf16x8*)&Al[(wm * 64 + mt * 16 + col16) * 72 + kh * 32 + quad * 8];
#pragma unroll
            for (int nt = 0; nt < 2; ++nt) {
                bf16x8 bfr = *(const bf16x8*)&Bl[(wn * 32 + nt * 16 + col16) * 72 + kh * 32 + quad * 8];
#pragma unroll
                for (int mt = 0; mt < 4; ++mt)
                    acc[mt][nt] = MFMA16(af[mt], bfr, acc[mt][nt]);
            }
        }
    }

    // epilogue: bias, Qbf store, ||q||^2 partials, LDS transpose for QT
    const int hh = wn >> 1;                     // head half within tile
    f32x4 ssum[4];
#pragma unroll
    for (int mt = 0; mt < 4; ++mt) ssum[mt] = z4;

    u16 qv16[2][4][4];
#pragma unroll
    for (int nt = 0; nt < 2; ++nt) {
        int col = bn * 128 + wn * 32 + nt * 16 + col16;
        float bqv = bq[col];
#pragma unroll
        for (int mt = 0; mt < 4; ++mt) {
            int row0 = bm * 128 + wm * 64 + mt * 16 + quad * 4;
#pragma unroll
            for (int rr = 0; rr < 4; ++rr) {
                float qv = acc[mt][nt][rr] + bqv;
                ssum[mt][rr] += qv * qv;
                u16 bv = f2bf(qv);
                qv16[nt][mt][rr] = bv;
                Qbf[(size_t)(row0 + rr) * D_DIM + col] = bv;
            }
        }
    }
    float vred[4][4];
#pragma unroll
    for (int mt = 0; mt < 4; ++mt)
#pragma unroll
        for (int rr = 0; rr < 4; ++rr) {
            float v = ssum[mt][rr];
            v += __shfl_xor(v, 1); v += __shfl_xor(v, 2);
            v += __shfl_xor(v, 4); v += __shfl_xor(v, 8);
            vred[mt][rr] = v;
        }
    if (col16 == 0) {
#pragma unroll
        for (int mt = 0; mt < 4; ++mt)
#pragma unroll
            for (int rr = 0; rr < 4; ++rr)
                sqp[wn * 128 + wm * 64 + mt * 16 + quad * 4 + rr] = vred[mt][rr];
    }
    __syncthreads();   // MFMA frag reads done; Al/Bl reusable; sqp visible

    // transpose: Td[head][d][s_local], stride 130 u16
    u16* Td = (u16*)smem;
#pragma unroll
    for (int nt = 0; nt < 2; ++nt) {
        int dloc = (wn & 1) * 32 + nt * 16 + col16;
#pragma unroll
        for (int mt = 0; mt < 4; ++mt) {
            int sl = wm * 64 + mt * 16 + quad * 4;
#pragma unroll
            for (int rr = 0; rr < 4; ++rr)
                Td[(hh * 64 + dloc) * 130 + sl + rr] = qv16[nt][mt][rr];
        }
    }
    __syncthreads();

    const int bb = (bm * 128) >> 11, s0 = (bm * 128) & 2047;
    if (tid < 256) {
        int r = tid & 127, hh2 = tid >> 7;
        float v = sqp[(2 * hh2) * 128 + r] + sqp[(2 * hh2 + 1) * 128 + r];
        int sidx = s0 + r;
        float o = mask[bb * S_LEN + sidx] ? v * C_SQ : 1e30f;
        sq05[((size_t)(bb * NH + bn * 2 + hh2)) * S_LEN + sidx] = o;
    }
    {
        int dr = tid >> 2, ch = tid & 3;
        int hh3 = dr >> 6, d = dr & 63;
        u16* dst = QT + ((size_t)(bb * NH + bn * 2 + hh3) * DHEAD + d) * S_LEN + s0 + ch * 32;
        const u16* src = Td + (hh3 * 64 + d) * 130 + ch * 32;
#pragma unroll
        for (int i = 0; i < 4; ++i)
            *(u16x8*)(dst + i * 8) = *(const u16x8*)(src + i * 8);
    }
}

// ---------------------------------------------------------------------------
// MEGA-2: blocks 0..511 = fused L2 attention.
//         8 waves = wq(4 q-quarters of 32 rows, nq=2) x wk(2 key halves of 64,
//         R0-verified kt/kbh algebra). Per-wave state halved vs R10 so
//         4 waves/SIMD fit WITHOUT spilling (R11: spills at 188 regs/wave).
//         blocks 512..767 = W2 fold (512-thread version, R11-verified).
__global__ __launch_bounds__(512, 4) void k_mega2(
    const u16* __restrict__ Qbf, const u16* __restrict__ QT,
    const float* __restrict__ sq05, u16* __restrict__ attnO,
    const float* __restrict__ Mpart, const float* __restrict__ Wout,
    u16* __restrict__ W2) {
    __shared__ __align__(16) char smem[34816];
    const int tid = threadIdx.x;

    if (blockIdx.x >= 512) {
        // ---------------- precomp_W2 path (512-thread, R11-verified) --------
        const int id = blockIdx.x - 512;
        const int ob = id & 15, h = id >> 4;
        float* Ms = (float*)smem;              // [64][65]
        float* Ws = (float*)(smem + 16640);    // [64][65]
        {
            int rr = tid >> 3, seg = tid & 7;
            const size_t mo = ((size_t)(h * 64 + rr)) * 64 + seg * 8;
            const float* ws = Wout + (size_t)(ob * 64 + rr) * D_DIM + h * DHEAD + seg * 8;
#pragma unroll
            for (int e = 0; e < 8; ++e) {
                float s = 0.f;
#pragma unroll
                for (int k = 0; k < 8; ++k) s += Mpart[mo + e + (size_t)k * 65536];
                Ms[rr * 65 + seg * 8 + e] = s;
                Ws[rr * 65 + seg * 8 + e] = ws[e];
            }
        }
        __syncthreads();
        int j = tid & 63, o0 = (tid >> 6) * 8;
        for (int oo = o0; oo < o0 + 8; ++oo) {
            float acc = 0.f;
#pragma unroll
            for (int f = 0; f < 64; ++f) acc += Ms[j * 65 + f] * Ws[oo * 65 + f];
            W2[(size_t)(ob * 64 + oo) * D_DIM + h * DHEAD + j] = f2bf(acc);
        }
        return;
    }

    // ---------------- flash path: 8 waves, halved per-wave state ----------
    u16* Kt  = (u16*)smem;              // [128][64] u16, xor-swizzled cols
    u16* KtT = (u16*)(smem + 16384);    // [64][128] u16, xor-swizzled cols
    float* sql = (float*)(smem + 32768);// [128]

    const int lane = tid & 63, w = tid >> 6;
    const int col16 = lane & 15, quad = lane >> 4;
    const int wq = w & 3, wk = w >> 2;   // wq 0..3 (32-row q quarters), wk 0..1 (64-key halves)
    const int bh = blockIdx.x & 31;      // (b,h) in low bits -> same XCD
    const int qt = blockIdx.x >> 5;
    const int h = bh & 15;
    const int b = bh >> 4;
    const u16* qbase = Qbf + (size_t)b * S_LEN * D_DIM + h * DHEAD;
    const u16* qtbase = QT + ((size_t)(b * NH + h)) * DHEAD * S_LEN;
    const float* sqb = sq05 + ((size_t)(b * NH + h)) * S_LEN;

    // loop-invariant Q^T B-fragments (global, once): rows qt*128 + wq*32 + nq*16 + col16
    bf16x8 qb[2][2];
#pragma unroll
    for (int nq = 0; nq < 2; ++nq)
#pragma unroll
        for (int k0 = 0; k0 < 2; ++k0)
            qb[nq][k0] = *(const bf16x8*)(qbase +
                (size_t)(qt * 128 + wq * 32 + nq * 16 + col16) * D_DIM + k0 * 32 + quad * 8);

    // Kt read offsets (R0-verified, wk = 64-key half): krow = krow00 + kt*2048 + kbh*256
    const int r00 = wk * 64 + (col16 >> 2) * 8 + (col16 & 3);
    const int swzA = (col16 & 3) | (((col16 >> 2) & 1) << 2);
    const int krow00 = r00 * 64 + (quad ^ swzA) * 8;
    const int sq00 = wk * 64 + quad * 8;
    int vrow[4];
#pragma unroll
    for (int dblk = 0; dblk < 4; ++dblk) {
        int rT = dblk * 16 + col16;
        vrow[dblk] = rT * 128 + ((wk * 8 + quad) ^ (rT & 7)) * 8;
    }

    // staging assignments (512 threads, 2 chunks each; R11-verified)
    const int kr = tid >> 2, ks = tid & 3;
    const int td = tid >> 3, ts = tid & 7;
    const int kswz = (kr & 3) | (((kr >> 3) & 1) << 2);
    const int tswz = td & 7;
    const u16* ksrc = qbase + (size_t)kr * D_DIM + ks * 16;
    const u16* tsrc = qtbase + (size_t)td * S_LEN + ts * 16;

    u16x8 pk[2], pt[2];
    float sv = 0.f;
#pragma unroll
    for (int i = 0; i < 2; ++i) pk[i] = *(const u16x8*)(ksrc + i * 8);
#pragma unroll
    for (int i = 0; i < 2; ++i) pt[i] = *(const u16x8*)(tsrc + i * 8);
    if (tid < 128) sv = sqb[tid];

    f32x4 Oacc[4][2], lacc[2];
    const f32x4 z4 = {0.f, 0.f, 0.f, 0.f};
#pragma unroll
    for (int n = 0; n < 2; ++n) {
        lacc[n] = z4;
#pragma unroll
        for (int d = 0; d < 4; ++d) Oacc[d][n] = z4;
    }
    bf16x8 ones;
    {
        union { u16x8 u; bf16x8 b; } cv;
#pragma unroll
        for (int e = 0; e < 8; ++e) cv.u[e] = 0x3F80;
        ones = cv.b;
    }

    for (int j = 0; j < S_LEN / 128; ++j) {
        __syncthreads();
#pragma unroll
        for (int i = 0; i < 2; ++i)
            *(u16x8*)(Kt + kr * 64 + ((ks * 2 + i) ^ kswz) * 8) = pk[i];
#pragma unroll
        for (int i = 0; i < 2; ++i)
            *(u16x8*)(KtT + td * 128 + ((ts * 2 + i) ^ tswz) * 8) = pt[i];
        if (tid < 128) sql[tid] = sv;
        __syncthreads();

        int jn = (j + 1) & 15;
        {
            const u16* kn = ksrc + (size_t)jn * 128 * D_DIM;
            const u16* tn = tsrc + (size_t)jn * 128;
#pragma unroll
            for (int i = 0; i < 2; ++i) pk[i] = *(const u16x8*)(kn + i * 8);
#pragma unroll
            for (int i = 0; i < 2; ++i) pt[i] = *(const u16x8*)(tn + i * 8);
            if (tid < 128) sv = sqb[jn * 128 + tid];
        }

        // two key-half rounds over this wave's 64 keys: 32 keys x 32 q each
        for (int kt = 0; kt < 2; ++kt) {
            f32x4 sacc[2][2];
#pragma unroll
            for (int kbh = 0; kbh < 2; ++kbh)
#pragma unroll
                for (int nq = 0; nq < 2; ++nq) sacc[kbh][nq] = z4;
#pragma unroll
            for (int kbh = 0; kbh < 2; ++kbh) {
                int kro = krow00 + kt * 2048 + kbh * 256;
                bf16x8 a0 = *(const bf16x8*)(Kt + kro);
                bf16x8 a1 = *(const bf16x8*)(Kt + (kro ^ 32));
#pragma unroll
                for (int nq = 0; nq < 2; ++nq) {
                    sacc[kbh][nq] = MFMA16(a0, qb[nq][0], sacc[kbh][nq]);
                    sacc[kbh][nq] = MFMA16(a1, qb[nq][1], sacc[kbh][nq]);
                }
            }

            // hoist V-fragment LDS reads: latency hides under the exp chain
            bf16x8 va[4];
#pragma unroll
            for (int dblk = 0; dblk < 4; ++dblk)
                va[dblk] = *(const bf16x8*)(KtT + (vrow[dblk] ^ (kt * 32)));

            u32 pf[2][4];
#pragma unroll
            for (int kbh = 0; kbh < 2; ++kbh) {
                f32x4 sqv = *(const f32x4*)(sql + sq00 + kt * 32 + kbh * 4);
#pragma unroll
                for (int nq = 0; nq < 2; ++nq) {
                    float p0 = EXP2(fmaf(sacc[kbh][nq][0], C_QK, -sqv[0]));
                    float p1 = EXP2(fmaf(sacc[kbh][nq][1], C_QK, -sqv[1]));
                    float p2 = EXP2(fmaf(sacc[kbh][nq][2], C_QK, -sqv[2]));
                    float p3 = EXP2(fmaf(sacc[kbh][nq][3], C_QK, -sqv[3]));
                    pf[nq][kbh * 2]     = pack_bf(p0, p1);
                    pf[nq][kbh * 2 + 1] = pack_bf(p2, p3);
                }
            }

#pragma unroll
            for (int nq = 0; nq < 2; ++nq) {
                union { u32 u[4]; bf16x8 b; } pb;
#pragma unroll
                for (int i = 0; i < 4; ++i) pb.u[i] = pf[nq][i];
                lacc[nq] = MFMA16(ones, pb.b, lacc[nq]);   // key-sums, rows replicated
#pragma unroll
                for (int dblk = 0; dblk < 4; ++dblk)
                    Oacc[dblk][nq] = MFMA16(va[dblk], pb.b, Oacc[dblk][nq]);
            }
        }
    }

    // cross-wave (key-half) combine + epilogue: 32 groups x 64 lanes
    __syncthreads();
    float* Obuf = (float*)smem;                 // [4wq][4dblk][2nq][64] f32x4 = 32 KB
    float* lred = (float*)(smem + 32768);       // [4wq][2nq][64] f32 = 2 KB
    if (wk == 1) {
#pragma unroll
        for (int dblk = 0; dblk < 4; ++dblk)
#pragma unroll
            for (int nq = 0; nq < 2; ++nq)
                *(f32x4*)(Obuf + ((wq * 8 + dblk * 2 + nq) * 64 + lane) * 4) = Oacc[dblk][nq];
#pragma unroll
        for (int nq = 0; nq < 2; ++nq)
            lred[(wq * 2 + nq) * 64 + lane] = lacc[nq][0];
    }
    __syncthreads();
    if (wk == 0) {
        float rinv[2];
#pragma unroll
        for (int nq = 0; nq < 2; ++nq)
            rinv[nq] = 1.f / (lacc[nq][0] + lred[(wq * 2 + nq) * 64 + lane]);
        u16* obase = attnO + (size_t)b * S_LEN * D_DIM + h * DHEAD;
#pragma unroll
        for (int dblk = 0; dblk < 4; ++dblk)
#pragma unroll
            for (int nq = 0; nq < 2; ++nq) {
                f32x4 o = Oacc[dblk][nq] + *(const f32x4*)(Obuf + ((wq * 8 + dblk * 2 + nq) * 64 + lane) * 4);
                int q = qt * 128 + wq * 32 + nq * 16 + col16;
                u16x4 pkk;
#pragma unroll
                for (int rr = 0; rr < 4; ++rr) pkk[rr] = f2bf(o[rr] * rinv[nq]);
                *(u16x4*)(obase + (size_t)q * D_DIM + dblk * 16 + quad * 4) = pkk;
            }
    }
}

// ---------------------------------------------------------------------------
// Output GEMM, 64x128 tile, 256 threads, grid (64,8) = 512 blocks (2/CU):
// out[s,o] = x[s,o] + bout[o] + attnO·W2^T
__global__ __launch_bounds__(256, 4) void k_oproj(
    const u16* __restrict__ attnO, const u16* __restrict__ W2,
    const float* __restrict__ x, const float* __restrict__ bout, float* __restrict__ out) {
    __shared__ __align__(16) char smem[27648];
    u16* Al = (u16*)smem;              // [64][72]
    u16* Bl = (u16*)(smem + 9216);     // [128][72]
    const int tid = threadIdx.x, lane = tid & 63, wn = tid >> 6;  // wn 0..3
    const int col16 = lane & 15, quad = lane >> 4;
    const int bm = blockIdx.x, bn = blockIdx.y;

    f32x4 acc[4][2];
    const f32x4 z4 = {0.f, 0.f, 0.f, 0.f};
#pragma unroll
    for (int i = 0; i < 4; ++i)
#pragma unroll
        for (int j = 0; j < 2; ++j) acc[i][j] = z4;

    // staging: A 64 rows x 64 cols (4 thr/row, 16 cols each);
    //          B 128 rows x 64 cols (2 thr/row, 32 cols each)
    const int arA = tid >> 2, asA = tid & 3;
    const int brB = tid >> 1, bsB = tid & 1;
    const u16* pa = attnO + (size_t)(bm * 64 + arA) * D_DIM + asA * 16;
    const u16* pb = W2 + (size_t)(bn * 128 + brB) * D_DIM + bsB * 32;

    u16x8 ra[2], rb[4];
#pragma unroll
    for (int i = 0; i < 2; ++i) ra[i] = *(const u16x8*)(pa + i * 8);
#pragma unroll
    for (int i = 0; i < 4; ++i) rb[i] = *(const u16x8*)(pb + i * 8);

    for (int k0 = 0; k0 < D_DIM; k0 += 64) {
        __syncthreads();
#pragma unroll
        for (int i = 0; i < 2; ++i) *(u16x8*)&Al[arA * 72 + asA * 16 + i * 8] = ra[i];
#pragma unroll
        for (int i = 0; i < 4; ++i) *(u16x8*)&Bl[brB * 72 + bsB * 32 + i * 8] = rb[i];
        __syncthreads();
        if (k0 + 64 < D_DIM) {
#pragma unroll
            for (int i = 0; i < 2; ++i) ra[i] = *(const u16x8*)(pa + k0 + 64 + i * 8);
#pragma unroll
            for (int i = 0; i < 4; ++i) rb[i] = *(const u16x8*)(pb + k0 + 64 + i * 8);
        }
#pragma unroll
        for (int kh = 0; kh < 2; ++kh) {
            bf16x8 af[4];
#pragma unroll
            for (int mt = 0; mt < 4; ++mt)
                af[mt] = *(const bf16x8*)&Al[(mt * 16 + col16) * 72 + kh * 32 + quad * 8];
#pragma unroll
            for (int nt = 0; nt < 2; ++nt) {
                bf16x8 bfr = *(const bf16x8*)&Bl[(wn * 32 + nt * 16 + col16) * 72 + kh * 32 + quad * 8];
#pragma unroll
                for (int mt = 0; mt < 4; ++mt)
                    acc[mt][nt] = MFMA16(af[mt], bfr, acc[mt][nt]);
            }
        }
    }
#pragma unroll
    for (int nt = 0; nt < 2; ++nt) {
        int col = bn * 128 + wn * 32 + nt * 16 + col16;
        float bv = bout[col];
#pragma unroll
        for (int mt = 0; mt < 4; ++mt) {
            int row0 = bm * 64 + mt * 16 + quad * 4;
#pragma unroll
            for (int rr = 0; rr < 4; ++rr) {
                size_t idx = (size_t)(row0 + rr) * D_DIM + col;
                out[idx] = acc[mt][nt][rr] + x[idx] + bv;
            }
        }
    }
}

// ---------------------------------------------------------------------------
extern "C" void kernel_launch(void* const* d_in, const int* in_sizes, int n_in,
                              void* d_out, int out_size, void* d_ws, size_t ws_size,
                              hipStream_t stream) {
    const float* x    = (const float*)d_in[0];
    const float* Wq   = (const float*)d_in[1];
    const float* bq   = (const float*)d_in[2];
    const float* Wv   = (const float*)d_in[3];
    const float* Wout = (const float*)d_in[4];
    const float* bout = (const float*)d_in[5];
    const int*   mask = (const int*)d_in[6];
    float* out = (float*)d_out;

    char* ws = (char*)d_ws;
    u16*   Qbf   = (u16*)(ws);                         // 8 MB
    u16*   QT    = (u16*)(ws + (8u << 20));            // 8 MB
    u16*   attnO = (u16*)(ws + (16u << 20));           // 8 MB (aliases xbf)
    u16*   W2    = (u16*)(ws + (24u << 20));           // 2 MB (aliases Wqbf)
    float* Mpart = (float*)(ws + (26u << 20));         // 2 MB (8 partials)
    float* sq05  = (float*)(ws + (28u << 20));         // 256 KB
    // bf16 operand staging: stream-ordered aliases (read before overwrite)
    u16*   xbf   = attnO;   // written by k_prep, read by k_mega1, then attnO
    u16*   Wqbf  = W2;      // written by k_prep, read by k_mega1, then W2

    k_prep<<<dim3(2048), dim3(256), 0, stream>>>(x, Wq, xbf, Wqbf);
    k_mega1<<<dim3(384), dim3(512), 0, stream>>>(xbf, Wqbf, Wq, Wv, bq, mask, Qbf, QT, sq05, Mpart);
    k_mega2<<<dim3(768), dim3(512), 0, stream>>>(Qbf, QT, sq05, attnO, Mpart, Wout, W2);
    k_oproj<<<dim3(64, 8), dim3(256), 0, stream>>>(attnO, W2, x, bout, out);
}

// Round 13
// 179.040 us; speedup vs baseline: 2.5226x; 1.0851x over previous
//
#include <hip/hip_runtime.h>

#define S_LEN 2048
#define D_DIM 1024
#define NH    16
#define DHEAD 64

typedef float f32x4 __attribute__((ext_vector_type(4)));
typedef __bf16 bf16x8 __attribute__((ext_vector_type(8)));
typedef unsigned short u16;
typedef unsigned int u32;
typedef unsigned short u16x8 __attribute__((ext_vector_type(8)));
typedef unsigned short u16x4 __attribute__((ext_vector_type(4)));

__device__ __forceinline__ u16 f2bf(float f) {
    union { float f; unsigned u; } c; c.f = f;
    unsigned u = c.u + 0x7fffu + ((c.u >> 16) & 1u);
    return (u16)(u >> 16);
}

// pack two f32 into one u32 of 2 bf16 via v_cvt_pk_bf16_f32.
// NOTE: lo/hi placement swapped vs naming on gfx950 (R8/R9 A/B). Safe ONLY
// where BOTH MFMA operands get the identical within-pair K permutation
// (dot-product invariant) -- i.e. operand pre-packing (k_prep). NOT safe for
// one-sided packs like the P->PV path (R1/R7/R8 failures).
__device__ __forceinline__ u32 cvtpk(float lo, float hi) {
    u32 r;
    asm("v_cvt_pk_bf16_f32 %0, %1, %2" : "=v"(r) : "v"(lo), "v"(hi));
    return r;
}

// pack two f32 into bf16 pair (truncation; bit-exact placement, verified)
__device__ __forceinline__ u32 pack_bf(float lo, float hi) {
    union { float f; u32 u; } a, b; a.f = lo; b.f = hi;
    return (b.u & 0xFFFF0000u) | (a.u >> 16);
}

#if __has_builtin(__builtin_amdgcn_exp2f)
#define EXP2(x) __builtin_amdgcn_exp2f(x)
#else
#define EXP2(x) exp2f(x)
#endif

// 0.25*log2(e), 0.125*log2(e)
#define C_QK  0.36067376022224085f
#define C_SQ  0.18033688011112043f

#define MFMA16(a, b, c) __builtin_amdgcn_mfma_f32_16x16x32_bf16((a), (b), (c), 0, 0, 0)

// ---------------------------------------------------------------------------
// PREP: convert x (4M f32) and Wq (1M f32) to bf16 workspaces.
__global__ __launch_bounds__(256) void k_prep(
    const float* __restrict__ x, const float* __restrict__ Wq,
    u16* __restrict__ xbf, u16* __restrict__ Wqbf) {
    const size_t NX = (size_t)2 * S_LEN * D_DIM / 8;   // 524288 chunks of 8
    const size_t NW = (size_t)D_DIM * D_DIM / 8;       // 131072 chunks
    for (size_t c = (size_t)blockIdx.x * 256 + threadIdx.x; c < NX + NW;
         c += (size_t)gridDim.x * 256) {
        const float* src; u16* dst; size_t off;
        if (c < NX) { src = x;  dst = xbf;  off = c * 8; }
        else        { src = Wq; dst = Wqbf; off = (c - NX) * 8; }
        f32x4 a = *(const f32x4*)(src + off);
        f32x4 b = *(const f32x4*)(src + off + 4);
        union { u32 w[4]; u16x8 v; } o;
        o.w[0] = cvtpk(a[0], a[1]); o.w[1] = cvtpk(a[2], a[3]);
        o.w[2] = cvtpk(b[0], b[1]); o.w[3] = cvtpk(b[2], b[3]);
        *(u16x8*)(dst + off) = o.v;
    }
}

// ---------------------------------------------------------------------------
// MEGA-1: blocks 0..511 = Q projection, 64x128 tile, 256 thr (oproj-verified
//         GEMM core; 2 blocks/CU). bm = 64-row s tile (0..63), bn = 2-head
//         group (0..7). blocks 512..639 = precomp_M (256-thread version).
__global__ __launch_bounds__(256, 4) void k_mega1(
    const u16* __restrict__ xbf, const u16* __restrict__ Wqbf,
    const float* __restrict__ Wq, const float* __restrict__ Wv,
    const float* __restrict__ bq, const int* __restrict__ mask,
    u16* __restrict__ Qbf, u16* __restrict__ QT,
    float* __restrict__ sq05, float* __restrict__ Mpart) {
    __shared__ __align__(16) char smem[33792];
    const int tid = threadIdx.x;

    if (blockIdx.x >= 512) {
        // ---------------- precomp_M path (256 threads, 2x64-row chunks) -----
        const int id = blockIdx.x - 512;
        const int z = id & 7, h = id >> 3;
        float* Qp = (float*)smem;              // [64][64] f32 = 16384 B
        float* Vp = (float*)(smem + 16384);    // [64][64] f32 = 16384 B
        const int r = tid >> 2, seg = tid & 3;        // 64 rows, 4 thr/row, 16 f32 each
        const int j0 = (tid >> 4) * 4;         // 16 groups x 4 j's = 64
        const int f0 = (tid & 15) * 4;         // 16 groups x 4 f's = 64
        f32x4 acc[4];
#pragma unroll
        for (int jj = 0; jj < 4; ++jj) acc[jj] = (f32x4){0.f, 0.f, 0.f, 0.f};
        for (int c = 0; c < 2; ++c) {
            const int e0 = z * 128 + c * 64;
            __syncthreads();
            const float* q = Wq + (size_t)(e0 + r) * D_DIM + h * DHEAD + seg * 16;
            const float* v = Wv + (size_t)(e0 + r) * D_DIM + h * DHEAD + seg * 16;
#pragma unroll
            for (int i = 0; i < 4; ++i) {
                *(f32x4*)&Qp[r * 64 + seg * 16 + i * 4] = *(const f32x4*)(q + i * 4);
                *(f32x4*)&Vp[r * 64 + seg * 16 + i * 4] = *(const f32x4*)(v + i * 4);
            }
            __syncthreads();
#pragma unroll 4
            for (int e = 0; e < 64; ++e) {
                f32x4 vv = *(const f32x4*)&Vp[e * 64 + f0];
#pragma unroll
                for (int jj = 0; jj < 4; ++jj)
                    acc[jj] += Qp[e * 64 + j0 + jj] * vv;
            }
        }
        float* dst = Mpart + (size_t)z * 65536 + ((size_t)(h * 64 + j0)) * 64 + f0;
#pragma unroll
        for (int jj = 0; jj < 4; ++jj)
            *(f32x4*)(dst + (size_t)jj * 64) = acc[jj] * 0.125f;
        return;
    }

    // ---------------- qproj path: 64 rows x 128 cols, 4 waves ----------------
    u16* Al = (u16*)smem;              // [64][72]  = 9216 B
    u16* Bl = (u16*)(smem + 9216);     // [128][72] = 18432 B
    float* sqp = (float*)(smem + 27648); // [4][64] f32 = 1024 B

    const int lane = tid & 63, wn = tid >> 6;   // wn 0..3 (32-col quarters)
    const int col16 = lane & 15, quad = lane >> 4;
    const int bm = blockIdx.x & 63, bn = blockIdx.x >> 6;

    f32x4 acc[4][2];
    const f32x4 z4 = {0.f, 0.f, 0.f, 0.f};
#pragma unroll
    for (int i = 0; i < 4; ++i)
#pragma unroll
        for (int j = 0; j < 2; ++j) acc[i][j] = z4;

    // staging (oproj-verified pattern): A 64 rows (4 thr/row, 16 u16 each);
    //                                   B 128 rows (2 thr/row, 32 u16 each)
    const int arA = tid >> 2, asA = tid & 3;
    const int brB = tid >> 1, bsB = tid & 1;
    const u16* pa = xbf + (size_t)(bm * 64 + arA) * D_DIM + asA * 16;
    const u16* pb = Wqbf + (size_t)(bn * 128 + brB) * D_DIM + bsB * 32;

    u16x8 ra[2], rb[4];
#pragma unroll
    for (int i = 0; i < 2; ++i) ra[i] = *(const u16x8*)(pa + i * 8);
#pragma unroll
    for (int i = 0; i < 4; ++i) rb[i] = *(const u16x8*)(pb + i * 8);

    for (int k0 = 0; k0 < D_DIM; k0 += 64) {
        __syncthreads();
#pragma unroll
        for (int i = 0; i < 2; ++i) *(u16x8*)&Al[arA * 72 + asA * 16 + i * 8] = ra[i];
#pragma unroll
        for (int i = 0; i < 4; ++i) *(u16x8*)&Bl[brB * 72 + bsB * 32 + i * 8] = rb[i];
        __syncthreads();
        if (k0 + 64 < D_DIM) {
#pragma unroll
            for (int i = 0; i < 2; ++i) ra[i] = *(const u16x8*)(pa + k0 + 64 + i * 8);
#pragma unroll
            for (int i = 0; i < 4; ++i) rb[i] = *(const u16x8*)(pb + k0 + 64 + i * 8);
        }
#pragma unroll
        for (int kh = 0; kh < 2; ++kh) {
            bf16x8 af[4];
#pragma unroll
            for (int mt = 0; mt < 4; ++mt)
                af[mt] = *(const bf16x8*)&Al[(mt * 16 + col16) * 72 + kh * 32 + quad * 8];
#pragma unroll
            for (int nt = 0; nt < 2; ++nt) {
                bf16x8 bfr = *(const bf16x8*)&Bl[(wn * 32 + nt * 16 + col16) * 72 + kh * 32 + quad * 8];
#pragma unroll
                for (int mt = 0; mt < 4; ++mt)
                    acc[mt][nt] = MFMA16(af[mt], bfr, acc[mt][nt]);
            }
        }
    }

    // epilogue: bias, Qbf store, ||q||^2 partials, LDS transpose for QT
    const int hh = wn >> 1;                     // head half within 128-col tile
    f32x4 ssum[4];
#pragma unroll
    for (int mt = 0; mt < 4; ++mt) ssum[mt] = z4;

    u16 qv16[2][4][4];
#pragma unroll
    for (int nt = 0; nt < 2; ++nt) {
        int col = bn * 128 + wn * 32 + nt * 16 + col16;
        float bqv = bq[col];
#pragma unroll
        for (int mt = 0; mt < 4; ++mt) {
            int row0 = bm * 64 + mt * 16 + quad * 4;
#pragma unroll
            for (int rr = 0; rr < 4; ++rr) {
                float qv = acc[mt][nt][rr] + bqv;
                ssum[mt][rr] += qv * qv;
                u16 bv = f2bf(qv);
                qv16[nt][mt][rr] = bv;
                Qbf[(size_t)(row0 + rr) * D_DIM + col] = bv;
            }
        }
    }
    float vred[4][4];
#pragma unroll
    for (int mt = 0; mt < 4; ++mt)
#pragma unroll
        for (int rr = 0; rr < 4; ++rr) {
            float v = ssum[mt][rr];
            v += __shfl_xor(v, 1); v += __shfl_xor(v, 2);
            v += __shfl_xor(v, 4); v += __shfl_xor(v, 8);
            vred[mt][rr] = v;
        }
    if (col16 == 0) {
#pragma unroll
        for (int mt = 0; mt < 4; ++mt)
#pragma unroll
            for (int rr = 0; rr < 4; ++rr)
                sqp[wn * 64 + mt * 16 + quad * 4 + rr] = vred[mt][rr];
    }
    __syncthreads();   // MFMA frag reads done; Al/Bl reusable; sqp visible

    // transpose: Td[head_half][d][s_local], stride 66 u16 (64 + 2 pad)
    u16* Td = (u16*)smem;              // [128][66] u16 = 16896 B (< 27648)
#pragma unroll
    for (int nt = 0; nt < 2; ++nt) {
        int dloc = (wn & 1) * 32 + nt * 16 + col16;
#pragma unroll
        for (int mt = 0; mt < 4; ++mt) {
            int sl = mt * 16 + quad * 4;
#pragma unroll
            for (int rr = 0; rr < 4; ++rr)
                Td[(hh * 64 + dloc) * 66 + sl + rr] = qv16[nt][mt][rr];
        }
    }
    __syncthreads();

    const int bb = bm >> 5, s0 = (bm * 64) & 2047;
    if (tid < 128) {
        int r = tid & 63, hh2 = tid >> 6;
        float v = sqp[(2 * hh2) * 64 + r] + sqp[(2 * hh2 + 1) * 64 + r];
        int sidx = s0 + r;
        float o = mask[bb * S_LEN + sidx] ? v * C_SQ : 1e30f;
        sq05[((size_t)(bb * NH + bn * 2 + hh2)) * S_LEN + sidx] = o;
    }
    {
        int dr = tid >> 1, ch = tid & 1;
        int hh3 = dr >> 6, d = dr & 63;
        u16* dst = QT + ((size_t)(bb * NH + bn * 2 + hh3) * DHEAD + d) * S_LEN + s0 + ch * 32;
        const u16* src = Td + (hh3 * 64 + d) * 66 + ch * 32;
#pragma unroll
        for (int i = 0; i < 4; ++i)
            *(u16x8*)(dst + i * 8) = *(const u16x8*)(src + i * 8);
    }
}

// ---------------------------------------------------------------------------
// MEGA-2: blocks 0..511 = fused L2 attention (R9-verified structure, 64 us)
//         blocks 512..767 = W2[o,c] = (sum_z Mpart) · Wout fold
__global__ __launch_bounds__(256, 2) void k_mega2(
    const u16* __restrict__ Qbf, const u16* __restrict__ QT,
    const float* __restrict__ sq05, u16* __restrict__ attnO,
    const float* __restrict__ Mpart, const float* __restrict__ Wout,
    u16* __restrict__ W2) {
    __shared__ __align__(16) char smem[34816];
    const int tid = threadIdx.x;

    if (blockIdx.x >= 512) {
        // ---------------- precomp_W2 path ----------------
        const int id = blockIdx.x - 512;
        const int ob = id & 15, h = id >> 4;
        float* Ms = (float*)smem;              // [64][65]
        float* Ws = (float*)(smem + 16640);    // [64][65]
        {
            int rr = tid >> 2, seg = tid & 3;
            const size_t mo = ((size_t)(h * 64 + rr)) * 64 + seg * 16;
            const float* ws = Wout + (size_t)(ob * 64 + rr) * D_DIM + h * DHEAD + seg * 16;
#pragma unroll
            for (int e = 0; e < 16; ++e) {
                float s = 0.f;
#pragma unroll
                for (int k = 0; k < 8; ++k) s += Mpart[mo + e + (size_t)k * 65536];
                Ms[rr * 65 + seg * 16 + e] = s;
                Ws[rr * 65 + seg * 16 + e] = ws[e];
            }
        }
        __syncthreads();
        int j = tid & 63, o0 = (tid >> 6) * 16;
        for (int oo = o0; oo < o0 + 16; ++oo) {
            float acc = 0.f;
#pragma unroll
            for (int f = 0; f < 64; ++f) acc += Ms[j * 65 + f] * Ws[oo * 65 + f];
            W2[(size_t)(ob * 64 + oo) * D_DIM + h * DHEAD + j] = f2bf(acc);
        }
        return;
    }

    // ---------------- flash path ----------------
    u16* Kt  = (u16*)smem;              // [128][64] u16, xor-swizzled cols
    u16* KtT = (u16*)(smem + 16384);    // [64][128] u16, xor-swizzled cols
    float* sql = (float*)(smem + 32768);// [128]

    const int lane = tid & 63, w = tid >> 6;
    const int col16 = lane & 15, quad = lane >> 4;
    const int wq = w & 1, wk = w >> 1;
    const int bh = blockIdx.x & 31;      // (b,h) in low bits -> same XCD
    const int qt = blockIdx.x >> 5;
    const int h = bh & 15;
    const int b = bh >> 4;
    const u16* qbase = Qbf + (size_t)b * S_LEN * D_DIM + h * DHEAD;
    const u16* qtbase = QT + ((size_t)(b * NH + h)) * DHEAD * S_LEN;
    const float* sqb = sq05 + ((size_t)(b * NH + h)) * S_LEN;

    // loop-invariant Q^T B-fragments (global, once)
    bf16x8 qb[4][2];
#pragma unroll
    for (int nq = 0; nq < 4; ++nq)
#pragma unroll
        for (int k0 = 0; k0 < 2; ++k0)
            qb[nq][k0] = *(const bf16x8*)(qbase +
                (size_t)(qt * 128 + wq * 64 + nq * 16 + col16) * D_DIM + k0 * 32 + quad * 8);

    // Kt read offset closed form: krow(kt,kbh) = krow00 + kt*2048 + kbh*256
    const int r00 = wk * 64 + (col16 >> 2) * 8 + (col16 & 3);
    const int swzA = (col16 & 3) | (((col16 >> 2) & 1) << 2);
    const int krow00 = r00 * 64 + (quad ^ swzA) * 8;
    const int sq00 = wk * 64 + quad * 8;
    int vrow[4];
#pragma unroll
    for (int dblk = 0; dblk < 4; ++dblk) {
        int rT = dblk * 16 + col16;
        vrow[dblk] = rT * 128 + ((wk * 8 + quad) ^ (rT & 7)) * 8;
    }

    // staging assignments
    const int kr = tid >> 1, ks = tid & 1;
    const int td = tid >> 2, ts = tid & 3;
    const int kswz = (kr & 3) | (((kr >> 3) & 1) << 2);
    const int tswz = td & 7;
    const u16* ksrc = qbase + (size_t)kr * D_DIM + ks * 32;
    const u16* tsrc = qtbase + (size_t)td * S_LEN + ts * 32;

    u16x8 pk[4], pt[4];
    float sv = 0.f;
#pragma unroll
    for (int i = 0; i < 4; ++i) pk[i] = *(const u16x8*)(ksrc + i * 8);
#pragma unroll
    for (int i = 0; i < 4; ++i) pt[i] = *(const u16x8*)(tsrc + i * 8);
    if (tid < 128) sv = sqb[tid];

    f32x4 Oacc[4][4], lacc[4];
    const f32x4 z4 = {0.f, 0.f, 0.f, 0.f};
#pragma unroll
    for (int n = 0; n < 4; ++n) {
        lacc[n] = z4;
#pragma unroll
        for (int d = 0; d < 4; ++d) Oacc[d][n] = z4;
    }
    bf16x8 ones;
    {
        union { u16x8 u; bf16x8 b; } cv;
#pragma unroll
        for (int e = 0; e < 8; ++e) cv.u[e] = 0x3F80;
        ones = cv.b;
    }

    for (int j = 0; j < S_LEN / 128; ++j) {
        __syncthreads();
#pragma unroll
        for (int i = 0; i < 4; ++i)
            *(u16x8*)(Kt + kr * 64 + ((ks * 4 + i) ^ kswz) * 8) = pk[i];
#pragma unroll
        for (int i = 0; i < 4; ++i)
            *(u16x8*)(KtT + td * 128 + ((ts * 4 + i) ^ tswz) * 8) = pt[i];
        if (tid < 128) sql[tid] = sv;
        __syncthreads();

        int jn = (j + 1) & 15;
        {
            const u16* kn = ksrc + (size_t)jn * 128 * D_DIM;
            const u16* tn = tsrc + (size_t)jn * 128;
#pragma unroll
            for (int i = 0; i < 4; ++i) pk[i] = *(const u16x8*)(kn + i * 8);
#pragma unroll
            for (int i = 0; i < 4; ++i) pt[i] = *(const u16x8*)(tn + i * 8);
            if (tid < 128) sv = sqb[jn * 128 + tid];
        }

        // two key-half rounds: S^T (32 keys x 64 q) -> exp/pack -> PV
        for (int kt = 0; kt < 2; ++kt) {
            f32x4 sacc[2][4];
#pragma unroll
            for (int kbh = 0; kbh < 2; ++kbh)
#pragma unroll
                for (int nq = 0; nq < 4; ++nq) sacc[kbh][nq] = z4;
#pragma unroll
            for (int kbh = 0; kbh < 2; ++kbh) {
                int kro = krow00 + kt * 2048 + kbh * 256;
                bf16x8 a0 = *(const bf16x8*)(Kt + kro);
                bf16x8 a1 = *(const bf16x8*)(Kt + (kro ^ 32));
#pragma unroll
                for (int nq = 0; nq < 4; ++nq) {
                    sacc[kbh][nq] = MFMA16(a0, qb[nq][0], sacc[kbh][nq]);
                    sacc[kbh][nq] = MFMA16(a1, qb[nq][1], sacc[kbh][nq]);
                }
            }

            // hoist V-fragment LDS reads: latency hides under the exp chain
            bf16x8 va[4];
#pragma unroll
            for (int dblk = 0; dblk < 4; ++dblk)
                va[dblk] = *(const bf16x8*)(KtT + (vrow[dblk] ^ (kt * 32)));

            u32 pf[4][4];
#pragma unroll
            for (int kbh = 0; kbh < 2; ++kbh) {
                f32x4 sqv = *(const f32x4*)(sql + sq00 + kt * 32 + kbh * 4);
#pragma unroll
                for (int nq = 0; nq < 4; ++nq) {
                    float p0 = EXP2(fmaf(sacc[kbh][nq][0], C_QK, -sqv[0]));
                    float p1 = EXP2(fmaf(sacc[kbh][nq][1], C_QK, -sqv[1]));
                    float p2 = EXP2(fmaf(sacc[kbh][nq][2], C_QK, -sqv[2]));
                    float p3 = EXP2(fmaf(sacc[kbh][nq][3], C_QK, -sqv[3]));
                    pf[nq][kbh * 2]     = pack_bf(p0, p1);
                    pf[nq][kbh * 2 + 1] = pack_bf(p2, p3);
                }
            }

#pragma unroll
            for (int nq = 0; nq < 4; ++nq) {
                union { u32 u[4]; bf16x8 b; } pb;
#pragma unroll
                for (int i = 0; i < 4; ++i) pb.u[i] = pf[nq][i];
                lacc[nq] = MFMA16(ones, pb.b, lacc[nq]);   // key-sums, rows replicated
#pragma unroll
                for (int dblk = 0; dblk < 4; ++dblk)
                    Oacc[dblk][nq] = MFMA16(va[dblk], pb.b, Oacc[dblk][nq]);
            }
        }
    }

    // cross-wave (key-half) combine + epilogue
    __syncthreads();
    float* Obuf = (float*)smem;                 // [2][16][64] f32x4 = 32 KB
    float* lred = (float*)(smem + 32768);       // [2][4][64]
    if (wk == 1) {
#pragma unroll
        for (int dblk = 0; dblk < 4; ++dblk)
#pragma unroll
            for (int nq = 0; nq < 4; ++nq)
                *(f32x4*)(Obuf + ((wq * 16 + dblk * 4 + nq) * 64 + lane) * 4) = Oacc[dblk][nq];
#pragma unroll
        for (int nq = 0; nq < 4; ++nq)
            lred[(wq * 4 + nq) * 64 + lane] = lacc[nq][0];
    }
    __syncthreads();
    if (wk == 0) {
        float rinv[4];
#pragma unroll
        for (int nq = 0; nq < 4; ++nq)
            rinv[nq] = 1.f / (lacc[nq][0] + lred[(wq * 4 + nq) * 64 + lane]);
        u16* obase = attnO + (size_t)b * S_LEN * D_DIM + h * DHEAD;
#pragma unroll
        for (int dblk = 0; dblk < 4; ++dblk)
#pragma unroll
            for (int nq = 0; nq < 4; ++nq) {
                f32x4 o = Oacc[dblk][nq] + *(const f32x4*)(Obuf + ((wq * 16 + dblk * 4 + nq) * 64 + lane) * 4);
                int q = qt * 128 + wq * 64 + nq * 16 + col16;
                u16x4 pkk;
#pragma unroll
                for (int rr = 0; rr < 4; ++rr) pkk[rr] = f2bf(o[rr] * rinv[nq]);
                *(u16x4*)(obase + (size_t)q * D_DIM + dblk * 16 + quad * 4) = pkk;
            }
    }
}

// ---------------------------------------------------------------------------
// Output GEMM, 64x128 tile, 256 threads, grid (64,8) = 512 blocks (2/CU):
// out[s,o] = x[s,o] + bout[o] + attnO·W2^T
__global__ __launch_bounds__(256, 4) void k_oproj(
    const u16* __restrict__ attnO, const u16* __restrict__ W2,
    const float* __restrict__ x, const float* __restrict__ bout, float* __restrict__ out) {
    __shared__ __align__(16) char smem[27648];
    u16* Al = (u16*)smem;              // [64][72]
    u16* Bl = (u16*)(smem + 9216);     // [128][72]
    const int tid = threadIdx.x, lane = tid & 63, wn = tid >> 6;  // wn 0..3
    const int col16 = lane & 15, quad = lane >> 4;
    const int bm = blockIdx.x, bn = blockIdx.y;

    f32x4 acc[4][2];
    const f32x4 z4 = {0.f, 0.f, 0.f, 0.f};
#pragma unroll
    for (int i = 0; i < 4; ++i)
#pragma unroll
        for (int j = 0; j < 2; ++j) acc[i][j] = z4;

    // staging: A 64 rows x 64 cols (4 thr/row, 16 cols each);
    //          B 128 rows x 64 cols (2 thr/row, 32 cols each)
    const int arA = tid >> 2, asA = tid & 3;
    const int brB = tid >> 1, bsB = tid & 1;
    const u16* pa = attnO + (size_t)(bm * 64 + arA) * D_DIM + asA * 16;
    const u16* pb = W2 + (size_t)(bn * 128 + brB) * D_DIM + bsB * 32;

    u16x8 ra[2], rb[4];
#pragma unroll
    for (int i = 0; i < 2; ++i) ra[i] = *(const u16x8*)(pa + i * 8);
#pragma unroll
    for (int i = 0; i < 4; ++i) rb[i] = *(const u16x8*)(pb + i * 8);

    for (int k0 = 0; k0 < D_DIM; k0 += 64) {
        __syncthreads();
#pragma unroll
        for (int i = 0; i < 2; ++i) *(u16x8*)&Al[arA * 72 + asA * 16 + i * 8] = ra[i];
#pragma unroll
        for (int i = 0; i < 4; ++i) *(u16x8*)&Bl[brB * 72 + bsB * 32 + i * 8] = rb[i];
        __syncthreads();
        if (k0 + 64 < D_DIM) {
#pragma unroll
            for (int i = 0; i < 2; ++i) ra[i] = *(const u16x8*)(pa + k0 + 64 + i * 8);
#pragma unroll
            for (int i = 0; i < 4; ++i) rb[i] = *(const u16x8*)(pb + k0 + 64 + i * 8);
        }
#pragma unroll
        for (int kh = 0; kh < 2; ++kh) {
            bf16x8 af[4];
#pragma unroll
            for (int mt = 0; mt < 4; ++mt)
                af[mt] = *(const bf16x8*)&Al[(mt * 16 + col16) * 72 + kh * 32 + quad * 8];
#pragma unroll
            for (int nt = 0; nt < 2; ++nt) {
                bf16x8 bfr = *(const bf16x8*)&Bl[(wn * 32 + nt * 16 + col16) * 72 + kh * 32 + quad * 8];
#pragma unroll
                for (int mt = 0; mt < 4; ++mt)
                    acc[mt][nt] = MFMA16(af[mt], bfr, acc[mt][nt]);
            }
        }
    }
#pragma unroll
    for (int nt = 0; nt < 2; ++nt) {
        int col = bn * 128 + wn * 32 + nt * 16 + col16;
        float bv = bout[col];
#pragma unroll
        for (int mt = 0; mt < 4; ++mt) {
            int row0 = bm * 64 + mt * 16 + quad * 4;
#pragma unroll
            for (int rr = 0; rr < 4; ++rr) {
                size_t idx = (size_t)(row0 + rr) * D_DIM + col;
                out[idx] = acc[mt][nt][rr] + x[idx] + bv;
            }
        }
    }
}

// ---------------------------------------------------------------------------
extern "C" void kernel_launch(void* const* d_in, const int* in_sizes, int n_in,
                              void* d_out, int out_size, void* d_ws, size_t ws_size,
                              hipStream_t stream) {
    const float* x    = (const float*)d_in[0];
    const float* Wq   = (const float*)d_in[1];
    const float* bq   = (const float*)d_in[2];
    const float* Wv   = (const float*)d_in[3];
    const float* Wout = (const float*)d_in[4];
    const float* bout = (const float*)d_in[5];
    const int*   mask = (const int*)d_in[6];
    float* out = (float*)d_out;

    char* ws = (char*)d_ws;
    u16*   Qbf   = (u16*)(ws);                         // 8 MB
    u16*   QT    = (u16*)(ws + (8u << 20));            // 8 MB
    u16*   attnO = (u16*)(ws + (16u << 20));           // 8 MB (aliases xbf)
    u16*   W2    = (u16*)(ws + (24u << 20));           // 2 MB (aliases Wqbf)
    float* Mpart = (float*)(ws + (26u << 20));         // 2 MB (8 partials)
    float* sq05  = (float*)(ws + (28u << 20));         // 256 KB
    // bf16 operand staging: stream-ordered aliases (read before overwrite)
    u16*   xbf   = attnO;   // written by k_prep, read by k_mega1, then attnO
    u16*   Wqbf  = W2;      // written by k_prep, read by k_mega1, then W2

    k_prep<<<dim3(2048), dim3(256), 0, stream>>>(x, Wq, xbf, Wqbf);
    k_mega1<<<dim3(640), dim3(256), 0, stream>>>(xbf, Wqbf, Wq, Wv, bq, mask, Qbf, QT, sq05, Mpart);
    k_mega2<<<dim3(768), dim3(256), 0, stream>>>(Qbf, QT, sq05, attnO, Mpart, Wout, W2);
    k_oproj<<<dim3(64, 8), dim3(256), 0, stream>>>(attnO, W2, x, bout, out);
}

// Round 14
// 176.095 us; speedup vs baseline: 2.5648x; 1.0167x over previous
//
#include <hip/hip_runtime.h>

#define S_LEN 2048
#define D_DIM 1024
#define NH    16
#define DHEAD 64

typedef float f32x4 __attribute__((ext_vector_type(4)));
typedef __bf16 bf16x8 __attribute__((ext_vector_type(8)));
typedef unsigned short u16;
typedef unsigned int u32;
typedef unsigned short u16x8 __attribute__((ext_vector_type(8)));
typedef unsigned short u16x4 __attribute__((ext_vector_type(4)));

__device__ __forceinline__ u16 f2bf(float f) {
    union { float f; unsigned u; } c; c.f = f;
    unsigned u = c.u + 0x7fffu + ((c.u >> 16) & 1u);
    return (u16)(u >> 16);
}

// pack two f32 into one u32 of 2 bf16 via v_cvt_pk_bf16_f32.
// NOTE: lo/hi placement swapped vs naming on gfx950 (R8/R9 A/B). Safe ONLY
// where BOTH MFMA operands get the identical within-pair K permutation
// (dot-product invariant) -- i.e. operand pre-packing (k_prep). NOT safe for
// one-sided packs like the P->PV path (R1/R7/R8 failures).
__device__ __forceinline__ u32 cvtpk(float lo, float hi) {
    u32 r;
    asm("v_cvt_pk_bf16_f32 %0, %1, %2" : "=v"(r) : "v"(lo), "v"(hi));
    return r;
}

// pack two f32 into bf16 pair (truncation; bit-exact placement, verified)
__device__ __forceinline__ u32 pack_bf(float lo, float hi) {
    union { float f; u32 u; } a, b; a.f = lo; b.f = hi;
    return (b.u & 0xFFFF0000u) | (a.u >> 16);
}

#if __has_builtin(__builtin_amdgcn_exp2f)
#define EXP2(x) __builtin_amdgcn_exp2f(x)
#else
#define EXP2(x) exp2f(x)
#endif

// 0.25*log2(e), 0.125*log2(e)
#define C_QK  0.36067376022224085f
#define C_SQ  0.18033688011112043f

#define MFMA16(a, b, c) __builtin_amdgcn_mfma_f32_16x16x32_bf16((a), (b), (c), 0, 0, 0)

// ---------------------------------------------------------------------------
// PREP: convert x (4M f32) and Wq (1M f32) to bf16 workspaces.
__global__ __launch_bounds__(256) void k_prep(
    const float* __restrict__ x, const float* __restrict__ Wq,
    u16* __restrict__ xbf, u16* __restrict__ Wqbf) {
    const size_t NX = (size_t)2 * S_LEN * D_DIM / 8;   // 524288 chunks of 8
    const size_t NW = (size_t)D_DIM * D_DIM / 8;       // 131072 chunks
    for (size_t c = (size_t)blockIdx.x * 256 + threadIdx.x; c < NX + NW;
         c += (size_t)gridDim.x * 256) {
        const float* src; u16* dst; size_t off;
        if (c < NX) { src = x;  dst = xbf;  off = c * 8; }
        else        { src = Wq; dst = Wqbf; off = (c - NX) * 8; }
        f32x4 a = *(const f32x4*)(src + off);
        f32x4 b = *(const f32x4*)(src + off + 4);
        union { u32 w[4]; u16x8 v; } o;
        o.w[0] = cvtpk(a[0], a[1]); o.w[1] = cvtpk(a[2], a[3]);
        o.w[2] = cvtpk(b[0], b[1]); o.w[3] = cvtpk(b[2], b[3]);
        *(u16x8*)(dst + off) = o.v;
    }
}

// ---------------------------------------------------------------------------
// MEGA-1: blocks 0..511 = Q projection, 64x128 tile, 256 thr (R13-verified).
//         blocks 512..639 = precomp_M (256-thread version, R13-verified).
__global__ __launch_bounds__(256, 4) void k_mega1(
    const u16* __restrict__ xbf, const u16* __restrict__ Wqbf,
    const float* __restrict__ Wq, const float* __restrict__ Wv,
    const float* __restrict__ bq, const int* __restrict__ mask,
    u16* __restrict__ Qbf, u16* __restrict__ QT,
    float* __restrict__ sq05, float* __restrict__ Mpart) {
    __shared__ __align__(16) char smem[33792];
    const int tid = threadIdx.x;

    if (blockIdx.x >= 512) {
        // ---------------- precomp_M path (256 threads, 2x64-row chunks) -----
        const int id = blockIdx.x - 512;
        const int z = id & 7, h = id >> 3;
        float* Qp = (float*)smem;              // [64][64] f32 = 16384 B
        float* Vp = (float*)(smem + 16384);    // [64][64] f32 = 16384 B
        const int r = tid >> 2, seg = tid & 3;
        const int j0 = (tid >> 4) * 4;         // 16 groups x 4 j's = 64
        const int f0 = (tid & 15) * 4;         // 16 groups x 4 f's = 64
        f32x4 acc[4];
#pragma unroll
        for (int jj = 0; jj < 4; ++jj) acc[jj] = (f32x4){0.f, 0.f, 0.f, 0.f};
        for (int c = 0; c < 2; ++c) {
            const int e0 = z * 128 + c * 64;
            __syncthreads();
            const float* q = Wq + (size_t)(e0 + r) * D_DIM + h * DHEAD + seg * 16;
            const float* v = Wv + (size_t)(e0 + r) * D_DIM + h * DHEAD + seg * 16;
#pragma unroll
            for (int i = 0; i < 4; ++i) {
                *(f32x4*)&Qp[r * 64 + seg * 16 + i * 4] = *(const f32x4*)(q + i * 4);
                *(f32x4*)&Vp[r * 64 + seg * 16 + i * 4] = *(const f32x4*)(v + i * 4);
            }
            __syncthreads();
#pragma unroll 4
            for (int e = 0; e < 64; ++e) {
                f32x4 vv = *(const f32x4*)&Vp[e * 64 + f0];
#pragma unroll
                for (int jj = 0; jj < 4; ++jj)
                    acc[jj] += Qp[e * 64 + j0 + jj] * vv;
            }
        }
        float* dst = Mpart + (size_t)z * 65536 + ((size_t)(h * 64 + j0)) * 64 + f0;
#pragma unroll
        for (int jj = 0; jj < 4; ++jj)
            *(f32x4*)(dst + (size_t)jj * 64) = acc[jj] * 0.125f;
        return;
    }

    // ---------------- qproj path: 64 rows x 128 cols, 4 waves ----------------
    u16* Al = (u16*)smem;              // [64][72]  = 9216 B
    u16* Bl = (u16*)(smem + 9216);     // [128][72] = 18432 B
    float* sqp = (float*)(smem + 27648); // [4][64] f32 = 1024 B

    const int lane = tid & 63, wn = tid >> 6;   // wn 0..3 (32-col quarters)
    const int col16 = lane & 15, quad = lane >> 4;
    const int bm = blockIdx.x & 63, bn = blockIdx.x >> 6;

    f32x4 acc[4][2];
    const f32x4 z4 = {0.f, 0.f, 0.f, 0.f};
#pragma unroll
    for (int i = 0; i < 4; ++i)
#pragma unroll
        for (int j = 0; j < 2; ++j) acc[i][j] = z4;

    const int arA = tid >> 2, asA = tid & 3;
    const int brB = tid >> 1, bsB = tid & 1;
    const u16* pa = xbf + (size_t)(bm * 64 + arA) * D_DIM + asA * 16;
    const u16* pb = Wqbf + (size_t)(bn * 128 + brB) * D_DIM + bsB * 32;

    u16x8 ra[2], rb[4];
#pragma unroll
    for (int i = 0; i < 2; ++i) ra[i] = *(const u16x8*)(pa + i * 8);
#pragma unroll
    for (int i = 0; i < 4; ++i) rb[i] = *(const u16x8*)(pb + i * 8);

    for (int k0 = 0; k0 < D_DIM; k0 += 64) {
        __syncthreads();
#pragma unroll
        for (int i = 0; i < 2; ++i) *(u16x8*)&Al[arA * 72 + asA * 16 + i * 8] = ra[i];
#pragma unroll
        for (int i = 0; i < 4; ++i) *(u16x8*)&Bl[brB * 72 + bsB * 32 + i * 8] = rb[i];
        __syncthreads();
        if (k0 + 64 < D_DIM) {
#pragma unroll
            for (int i = 0; i < 2; ++i) ra[i] = *(const u16x8*)(pa + k0 + 64 + i * 8);
#pragma unroll
            for (int i = 0; i < 4; ++i) rb[i] = *(const u16x8*)(pb + k0 + 64 + i * 8);
        }
#pragma unroll
        for (int kh = 0; kh < 2; ++kh) {
            bf16x8 af[4];
#pragma unroll
            for (int mt = 0; mt < 4; ++mt)
                af[mt] = *(const bf16x8*)&Al[(mt * 16 + col16) * 72 + kh * 32 + quad * 8];
#pragma unroll
            for (int nt = 0; nt < 2; ++nt) {
                bf16x8 bfr = *(const bf16x8*)&Bl[(wn * 32 + nt * 16 + col16) * 72 + kh * 32 + quad * 8];
#pragma unroll
                for (int mt = 0; mt < 4; ++mt)
                    acc[mt][nt] = MFMA16(af[mt], bfr, acc[mt][nt]);
            }
        }
    }

    // epilogue: bias, Qbf store, ||q||^2 partials, LDS transpose for QT
    const int hh = wn >> 1;
    f32x4 ssum[4];
#pragma unroll
    for (int mt = 0; mt < 4; ++mt) ssum[mt] = z4;

    u16 qv16[2][4][4];
#pragma unroll
    for (int nt = 0; nt < 2; ++nt) {
        int col = bn * 128 + wn * 32 + nt * 16 + col16;
        float bqv = bq[col];
#pragma unroll
        for (int mt = 0; mt < 4; ++mt) {
            int row0 = bm * 64 + mt * 16 + quad * 4;
#pragma unroll
            for (int rr = 0; rr < 4; ++rr) {
                float qv = acc[mt][nt][rr] + bqv;
                ssum[mt][rr] += qv * qv;
                u16 bv = f2bf(qv);
                qv16[nt][mt][rr] = bv;
                Qbf[(size_t)(row0 + rr) * D_DIM + col] = bv;
            }
        }
    }
    float vred[4][4];
#pragma unroll
    for (int mt = 0; mt < 4; ++mt)
#pragma unroll
        for (int rr = 0; rr < 4; ++rr) {
            float v = ssum[mt][rr];
            v += __shfl_xor(v, 1); v += __shfl_xor(v, 2);
            v += __shfl_xor(v, 4); v += __shfl_xor(v, 8);
            vred[mt][rr] = v;
        }
    if (col16 == 0) {
#pragma unroll
        for (int mt = 0; mt < 4; ++mt)
#pragma unroll
            for (int rr = 0; rr < 4; ++rr)
                sqp[wn * 64 + mt * 16 + quad * 4 + rr] = vred[mt][rr];
    }
    __syncthreads();

    // transpose: Td[head_half][d][s_local], stride 66 u16 (64 + 2 pad)
    u16* Td = (u16*)smem;
#pragma unroll
    for (int nt = 0; nt < 2; ++nt) {
        int dloc = (wn & 1) * 32 + nt * 16 + col16;
#pragma unroll
        for (int mt = 0; mt < 4; ++mt) {
            int sl = mt * 16 + quad * 4;
#pragma unroll
            for (int rr = 0; rr < 4; ++rr)
                Td[(hh * 64 + dloc) * 66 + sl + rr] = qv16[nt][mt][rr];
        }
    }
    __syncthreads();

    const int bb = bm >> 5, s0 = (bm * 64) & 2047;
    if (tid < 128) {
        int r = tid & 63, hh2 = tid >> 6;
        float v = sqp[(2 * hh2) * 64 + r] + sqp[(2 * hh2 + 1) * 64 + r];
        int sidx = s0 + r;
        float o = mask[bb * S_LEN + sidx] ? v * C_SQ : 1e30f;
        sq05[((size_t)(bb * NH + bn * 2 + hh2)) * S_LEN + sidx] = o;
    }
    {
        int dr = tid >> 1, ch = tid & 1;
        int hh3 = dr >> 6, d = dr & 63;
        u16* dst = QT + ((size_t)(bb * NH + bn * 2 + hh3) * DHEAD + d) * S_LEN + s0 + ch * 32;
        const u16* src = Td + (hh3 * 64 + d) * 66 + ch * 32;
#pragma unroll
        for (int i = 0; i < 4; ++i)
            *(u16x8*)(dst + i * 8) = *(const u16x8*)(src + i * 8);
    }
}

// ---------------------------------------------------------------------------
// MEGA-2: blocks 0..255 = fused L2 attention, 2 q-tiles per block sharing one
//         staged K/V tile. 8 waves = sub(2 q-tiles) x wq(2) x wk(2); per-wave
//         compute = R9-verified code verbatim (qt = 2*(bid>>5) + sub).
//         Staging = R11/R12-verified 512-thread pattern. Epilogue = R9
//         epilogue run twice, serialized through shared Obuf.
//         blocks 256..511 = W2 fold (512-thread version, R11/R12-verified).
__global__ __launch_bounds__(512, 2) void k_mega2(
    const u16* __restrict__ Qbf, const u16* __restrict__ QT,
    const float* __restrict__ sq05, u16* __restrict__ attnO,
    const float* __restrict__ Mpart, const float* __restrict__ Wout,
    u16* __restrict__ W2) {
    __shared__ __align__(16) char smem[34816];
    const int tid = threadIdx.x;

    if (blockIdx.x >= 256) {
        // ---------------- precomp_W2 path (512-thread, R11-verified) --------
        const int id = blockIdx.x - 256;
        const int ob = id & 15, h = id >> 4;
        float* Ms = (float*)smem;              // [64][65]
        float* Ws = (float*)(smem + 16640);    // [64][65]
        {
            int rr = tid >> 3, seg = tid & 7;
            const size_t mo = ((size_t)(h * 64 + rr)) * 64 + seg * 8;
            const float* ws = Wout + (size_t)(ob * 64 + rr) * D_DIM + h * DHEAD + seg * 8;
#pragma unroll
            for (int e = 0; e < 8; ++e) {
                float s = 0.f;
#pragma unroll
                for (int k = 0; k < 8; ++k) s += Mpart[mo + e + (size_t)k * 65536];
                Ms[rr * 65 + seg * 8 + e] = s;
                Ws[rr * 65 + seg * 8 + e] = ws[e];
            }
        }
        __syncthreads();
        int j = tid & 63, o0 = (tid >> 6) * 8;
        for (int oo = o0; oo < o0 + 8; ++oo) {
            float acc = 0.f;
#pragma unroll
            for (int f = 0; f < 64; ++f) acc += Ms[j * 65 + f] * Ws[oo * 65 + f];
            W2[(size_t)(ob * 64 + oo) * D_DIM + h * DHEAD + j] = f2bf(acc);
        }
        return;
    }

    // ---------------- flash path: 8 waves, 2 q-tiles, shared K/V ----------
    u16* Kt  = (u16*)smem;              // [128][64] u16, xor-swizzled cols
    u16* KtT = (u16*)(smem + 16384);    // [64][128] u16, xor-swizzled cols
    float* sql = (float*)(smem + 32768);// [128]

    const int lane = tid & 63, w = tid >> 6;
    const int col16 = lane & 15, quad = lane >> 4;
    const int wq = w & 1, wk = (w >> 1) & 1, sub = w >> 2;
    const int bh = blockIdx.x & 31;      // (b,h) in low bits -> same XCD
    const int qt = (blockIdx.x >> 5) * 2 + sub;   // 0..15, 128-row tiles
    const int h = bh & 15;
    const int b = bh >> 4;
    const u16* qbase = Qbf + (size_t)b * S_LEN * D_DIM + h * DHEAD;
    const u16* qtbase = QT + ((size_t)(b * NH + h)) * DHEAD * S_LEN;
    const float* sqb = sq05 + ((size_t)(b * NH + h)) * S_LEN;

    // loop-invariant Q^T B-fragments (global, once)
    bf16x8 qb[4][2];
#pragma unroll
    for (int nq = 0; nq < 4; ++nq)
#pragma unroll
        for (int k0 = 0; k0 < 2; ++k0)
            qb[nq][k0] = *(const bf16x8*)(qbase +
                (size_t)(qt * 128 + wq * 64 + nq * 16 + col16) * D_DIM + k0 * 32 + quad * 8);

    // Kt read offset closed form (R9-verified): krow = krow00 + kt*2048 + kbh*256
    const int r00 = wk * 64 + (col16 >> 2) * 8 + (col16 & 3);
    const int swzA = (col16 & 3) | (((col16 >> 2) & 1) << 2);
    const int krow00 = r00 * 64 + (quad ^ swzA) * 8;
    const int sq00 = wk * 64 + quad * 8;
    int vrow[4];
#pragma unroll
    for (int dblk = 0; dblk < 4; ++dblk) {
        int rT = dblk * 16 + col16;
        vrow[dblk] = rT * 128 + ((wk * 8 + quad) ^ (rT & 7)) * 8;
    }

    // staging assignments (512 threads, 2 chunks each; R11/R12-verified)
    const int kr = tid >> 2, ks = tid & 3;
    const int td = tid >> 3, ts = tid & 7;
    const int kswz = (kr & 3) | (((kr >> 3) & 1) << 2);
    const int tswz = td & 7;
    const u16* ksrc = qbase + (size_t)kr * D_DIM + ks * 16;
    const u16* tsrc = qtbase + (size_t)td * S_LEN + ts * 16;

    u16x8 pk[2], pt[2];
    float sv = 0.f;
#pragma unroll
    for (int i = 0; i < 2; ++i) pk[i] = *(const u16x8*)(ksrc + i * 8);
#pragma unroll
    for (int i = 0; i < 2; ++i) pt[i] = *(const u16x8*)(tsrc + i * 8);
    if (tid < 128) sv = sqb[tid];

    f32x4 Oacc[4][4], lacc[4];
    const f32x4 z4 = {0.f, 0.f, 0.f, 0.f};
#pragma unroll
    for (int n = 0; n < 4; ++n) {
        lacc[n] = z4;
#pragma unroll
        for (int d = 0; d < 4; ++d) Oacc[d][n] = z4;
    }
    bf16x8 ones;
    {
        union { u16x8 u; bf16x8 b; } cv;
#pragma unroll
        for (int e = 0; e < 8; ++e) cv.u[e] = 0x3F80;
        ones = cv.b;
    }

    for (int j = 0; j < S_LEN / 128; ++j) {
        __syncthreads();
#pragma unroll
        for (int i = 0; i < 2; ++i)
            *(u16x8*)(Kt + kr * 64 + ((ks * 2 + i) ^ kswz) * 8) = pk[i];
#pragma unroll
        for (int i = 0; i < 2; ++i)
            *(u16x8*)(KtT + td * 128 + ((ts * 2 + i) ^ tswz) * 8) = pt[i];
        if (tid < 128) sql[tid] = sv;
        __syncthreads();

        int jn = (j + 1) & 15;
        {
            const u16* kn = ksrc + (size_t)jn * 128 * D_DIM;
            const u16* tn = tsrc + (size_t)jn * 128;
#pragma unroll
            for (int i = 0; i < 2; ++i) pk[i] = *(const u16x8*)(kn + i * 8);
#pragma unroll
            for (int i = 0; i < 2; ++i) pt[i] = *(const u16x8*)(tn + i * 8);
            if (tid < 128) sv = sqb[jn * 128 + tid];
        }

        // two key-half rounds: S^T (32 keys x 64 q) -> exp/pack -> PV
        for (int kt = 0; kt < 2; ++kt) {
            f32x4 sacc[2][4];
#pragma unroll
            for (int kbh = 0; kbh < 2; ++kbh)
#pragma unroll
                for (int nq = 0; nq < 4; ++nq) sacc[kbh][nq] = z4;
#pragma unroll
            for (int kbh = 0; kbh < 2; ++kbh) {
                int kro = krow00 + kt * 2048 + kbh * 256;
                bf16x8 a0 = *(const bf16x8*)(Kt + kro);
                bf16x8 a1 = *(const bf16x8*)(Kt + (kro ^ 32));
#pragma unroll
                for (int nq = 0; nq < 4; ++nq) {
                    sacc[kbh][nq] = MFMA16(a0, qb[nq][0], sacc[kbh][nq]);
                    sacc[kbh][nq] = MFMA16(a1, qb[nq][1], sacc[kbh][nq]);
                }
            }

            // hoist V-fragment LDS reads: latency hides under the exp chain
            bf16x8 va[4];
#pragma unroll
            for (int dblk = 0; dblk < 4; ++dblk)
                va[dblk] = *(const bf16x8*)(KtT + (vrow[dblk] ^ (kt * 32)));

            u32 pf[4][4];
#pragma unroll
            for (int kbh = 0; kbh < 2; ++kbh) {
                f32x4 sqv = *(const f32x4*)(sql + sq00 + kt * 32 + kbh * 4);
#pragma unroll
                for (int nq = 0; nq < 4; ++nq) {
                    float p0 = EXP2(fmaf(sacc[kbh][nq][0], C_QK, -sqv[0]));
                    float p1 = EXP2(fmaf(sacc[kbh][nq][1], C_QK, -sqv[1]));
                    float p2 = EXP2(fmaf(sacc[kbh][nq][2], C_QK, -sqv[2]));
                    float p3 = EXP2(fmaf(sacc[kbh][nq][3], C_QK, -sqv[3]));
                    pf[nq][kbh * 2]     = pack_bf(p0, p1);
                    pf[nq][kbh * 2 + 1] = pack_bf(p2, p3);
                }
            }

#pragma unroll
            for (int nq = 0; nq < 4; ++nq) {
                union { u32 u[4]; bf16x8 b; } pb;
#pragma unroll
                for (int i = 0; i < 4; ++i) pb.u[i] = pf[nq][i];
                lacc[nq] = MFMA16(ones, pb.b, lacc[nq]);   // key-sums, rows replicated
#pragma unroll
                for (int dblk = 0; dblk < 4; ++dblk)
                    Oacc[dblk][nq] = MFMA16(va[dblk], pb.b, Oacc[dblk][nq]);
            }
        }
    }

    // cross-wave (key-half) combine + epilogue: R9 epilogue per sub-tile,
    // serialized through the shared Obuf (uniform barriers).
    __syncthreads();
    float* Obuf = (float*)smem;                 // [2][16][64] f32x4 = 32 KB
    float* lred = (float*)(smem + 32768);       // [2][4][64]
    u16* obase = attnO + (size_t)b * S_LEN * D_DIM + h * DHEAD;
    for (int s = 0; s < 2; ++s) {
        if (sub == s && wk == 1) {
#pragma unroll
            for (int dblk = 0; dblk < 4; ++dblk)
#pragma unroll
                for (int nq = 0; nq < 4; ++nq)
                    *(f32x4*)(Obuf + ((wq * 16 + dblk * 4 + nq) * 64 + lane) * 4) = Oacc[dblk][nq];
#pragma unroll
            for (int nq = 0; nq < 4; ++nq)
                lred[(wq * 4 + nq) * 64 + lane] = lacc[nq][0];
        }
        __syncthreads();
        if (sub == s && wk == 0) {
            float rinv[4];
#pragma unroll
            for (int nq = 0; nq < 4; ++nq)
                rinv[nq] = 1.f / (lacc[nq][0] + lred[(wq * 4 + nq) * 64 + lane]);
#pragma unroll
            for (int dblk = 0; dblk < 4; ++dblk)
#pragma unroll
                for (int nq = 0; nq < 4; ++nq) {
                    f32x4 o = Oacc[dblk][nq] + *(const f32x4*)(Obuf + ((wq * 16 + dblk * 4 + nq) * 64 + lane) * 4);
                    int q = qt * 128 + wq * 64 + nq * 16 + col16;
                    u16x4 pkk;
#pragma unroll
                    for (int rr = 0; rr < 4; ++rr) pkk[rr] = f2bf(o[rr] * rinv[nq]);
                    *(u16x4*)(obase + (size_t)q * D_DIM + dblk * 16 + quad * 4) = pkk;
                }
        }
        __syncthreads();
    }
}

// ---------------------------------------------------------------------------
// Output GEMM, 64x128 tile, 256 threads, grid (64,8) = 512 blocks (2/CU):
// out[s,o] = x[s,o] + bout[o] + attnO·W2^T
__global__ __launch_bounds__(256, 4) void k_oproj(
    const u16* __restrict__ attnO, const u16* __restrict__ W2,
    const float* __restrict__ x, const float* __restrict__ bout, float* __restrict__ out) {
    __shared__ __align__(16) char smem[27648];
    u16* Al = (u16*)smem;              // [64][72]
    u16* Bl = (u16*)(smem + 9216);     // [128][72]
    const int tid = threadIdx.x, lane = tid & 63, wn = tid >> 6;  // wn 0..3
    const int col16 = lane & 15, quad = lane >> 4;
    const int bm = blockIdx.x, bn = blockIdx.y;

    f32x4 acc[4][2];
    const f32x4 z4 = {0.f, 0.f, 0.f, 0.f};
#pragma unroll
    for (int i = 0; i < 4; ++i)
#pragma unroll
        for (int j = 0; j < 2; ++j) acc[i][j] = z4;

    const int arA = tid >> 2, asA = tid & 3;
    const int brB = tid >> 1, bsB = tid & 1;
    const u16* pa = attnO + (size_t)(bm * 64 + arA) * D_DIM + asA * 16;
    const u16* pb = W2 + (size_t)(bn * 128 + brB) * D_DIM + bsB * 32;

    u16x8 ra[2], rb[4];
#pragma unroll
    for (int i = 0; i < 2; ++i) ra[i] = *(const u16x8*)(pa + i * 8);
#pragma unroll
    for (int i = 0; i < 4; ++i) rb[i] = *(const u16x8*)(pb + i * 8);

    for (int k0 = 0; k0 < D_DIM; k0 += 64) {
        __syncthreads();
#pragma unroll
        for (int i = 0; i < 2; ++i) *(u16x8*)&Al[arA * 72 + asA * 16 + i * 8] = ra[i];
#pragma unroll
        for (int i = 0; i < 4; ++i) *(u16x8*)&Bl[brB * 72 + bsB * 32 + i * 8] = rb[i];
        __syncthreads();
        if (k0 + 64 < D_DIM) {
#pragma unroll
            for (int i = 0; i < 2; ++i) ra[i] = *(const u16x8*)(pa + k0 + 64 + i * 8);
#pragma unroll
            for (int i = 0; i < 4; ++i) rb[i] = *(const u16x8*)(pb + k0 + 64 + i * 8);
        }
#pragma unroll
        for (int kh = 0; kh < 2; ++kh) {
            bf16x8 af[4];
#pragma unroll
            for (int mt = 0; mt < 4; ++mt)
                af[mt] = *(const bf16x8*)&Al[(mt * 16 + col16) * 72 + kh * 32 + quad * 8];
#pragma unroll
            for (int nt = 0; nt < 2; ++nt) {
                bf16x8 bfr = *(const bf16x8*)&Bl[(wn * 32 + nt * 16 + col16) * 72 + kh * 32 + quad * 8];
#pragma unroll
                for (int mt = 0; mt < 4; ++mt)
                    acc[mt][nt] = MFMA16(af[mt], bfr, acc[mt][nt]);
            }
        }
    }
#pragma unroll
    for (int nt = 0; nt < 2; ++nt) {
        int col = bn * 128 + wn * 32 + nt * 16 + col16;
        float bv = bout[col];
#pragma unroll
        for (int mt = 0; mt < 4; ++mt) {
            int row0 = bm * 64 + mt * 16 + quad * 4;
#pragma unroll
            for (int rr = 0; rr < 4; ++rr) {
                size_t idx = (size_t)(row0 + rr) * D_DIM + col;
                out[idx] = acc[mt][nt][rr] + x[idx] + bv;
            }
        }
    }
}

// ---------------------------------------------------------------------------
extern "C" void kernel_launch(void* const* d_in, const int* in_sizes, int n_in,
                              void* d_out, int out_size, void* d_ws, size_t ws_size,
                              hipStream_t stream) {
    const float* x    = (const float*)d_in[0];
    const float* Wq   = (const float*)d_in[1];
    const float* bq   = (const float*)d_in[2];
    const float* Wv   = (const float*)d_in[3];
    const float* Wout = (const float*)d_in[4];
    const float* bout = (const float*)d_in[5];
    const int*   mask = (const int*)d_in[6];
    float* out = (float*)d_out;

    char* ws = (char*)d_ws;
    u16*   Qbf   = (u16*)(ws);                         // 8 MB
    u16*   QT    = (u16*)(ws + (8u << 20));            // 8 MB
    u16*   attnO = (u16*)(ws + (16u << 20));           // 8 MB (aliases xbf)
    u16*   W2    = (u16*)(ws + (24u << 20));           // 2 MB (aliases Wqbf)
    float* Mpart = (float*)(ws + (26u << 20));         // 2 MB (8 partials)
    float* sq05  = (float*)(ws + (28u << 20));         // 256 KB
    // bf16 operand staging: stream-ordered aliases (read before overwrite)
    u16*   xbf   = attnO;   // written by k_prep, read by k_mega1, then attnO
    u16*   Wqbf  = W2;      // written by k_prep, read by k_mega1, then W2

    k_prep<<<dim3(2048), dim3(256), 0, stream>>>(x, Wq, xbf, Wqbf);
    k_mega1<<<dim3(640), dim3(256), 0, stream>>>(xbf, Wqbf, Wq, Wv, bq, mask, Qbf, QT, sq05, Mpart);
    k_mega2<<<dim3(512), dim3(512), 0, stream>>>(Qbf, QT, sq05, attnO, Mpart, Wout, W2);
    k_oproj<<<dim3(64, 8), dim3(256), 0, stream>>>(attnO, W2, x, bout, out);
}

// Round 15
// 175.909 us; speedup vs baseline: 2.5675x; 1.0011x over previous
//
#include <hip/hip_runtime.h>

#define S_LEN 2048
#define D_DIM 1024
#define NH    16
#define DHEAD 64

typedef float f32x4 __attribute__((ext_vector_type(4)));
typedef __bf16 bf16x8 __attribute__((ext_vector_type(8)));
typedef unsigned short u16;
typedef unsigned int u32;
typedef unsigned short u16x8 __attribute__((ext_vector_type(8)));
typedef unsigned short u16x4 __attribute__((ext_vector_type(4)));

__device__ __forceinline__ u16 f2bf(float f) {
    union { float f; unsigned u; } c; c.f = f;
    unsigned u = c.u + 0x7fffu + ((c.u >> 16) & 1u);
    return (u16)(u >> 16);
}

// pack two f32 into one u32 of 2 bf16 via v_cvt_pk_bf16_f32.
// NOTE: lo/hi placement swapped vs naming on gfx950 (R8/R9 A/B). Safe ONLY
// where BOTH MFMA operands get the identical within-pair K permutation
// (dot-product invariant) -- i.e. operand pre-packing (k_prep). NOT safe for
// one-sided packs like the P->PV path (R1/R7/R8 failures).
__device__ __forceinline__ u32 cvtpk(float lo, float hi) {
    u32 r;
    asm("v_cvt_pk_bf16_f32 %0, %1, %2" : "=v"(r) : "v"(lo), "v"(hi));
    return r;
}

// pack two f32 into bf16 pair (truncation; bit-exact placement, verified)
__device__ __forceinline__ u32 pack_bf(float lo, float hi) {
    union { float f; u32 u; } a, b; a.f = lo; b.f = hi;
    return (b.u & 0xFFFF0000u) | (a.u >> 16);
}

#if __has_builtin(__builtin_amdgcn_exp2f)
#define EXP2(x) __builtin_amdgcn_exp2f(x)
#else
#define EXP2(x) exp2f(x)
#endif

// 0.25*log2(e), 0.125*log2(e)
#define C_QK  0.36067376022224085f
#define C_SQ  0.18033688011112043f

#define MFMA16(a, b, c) __builtin_amdgcn_mfma_f32_16x16x32_bf16((a), (b), (c), 0, 0, 0)

// ---------------------------------------------------------------------------
// PREP: convert x (4M f32) and Wq (1M f32) to bf16 workspaces.
__global__ __launch_bounds__(256) void k_prep(
    const float* __restrict__ x, const float* __restrict__ Wq,
    u16* __restrict__ xbf, u16* __restrict__ Wqbf) {
    const size_t NX = (size_t)2 * S_LEN * D_DIM / 8;   // 524288 chunks of 8
    const size_t NW = (size_t)D_DIM * D_DIM / 8;       // 131072 chunks
    for (size_t c = (size_t)blockIdx.x * 256 + threadIdx.x; c < NX + NW;
         c += (size_t)gridDim.x * 256) {
        const float* src; u16* dst; size_t off;
        if (c < NX) { src = x;  dst = xbf;  off = c * 8; }
        else        { src = Wq; dst = Wqbf; off = (c - NX) * 8; }
        f32x4 a = *(const f32x4*)(src + off);
        f32x4 b = *(const f32x4*)(src + off + 4);
        union { u32 w[4]; u16x8 v; } o;
        o.w[0] = cvtpk(a[0], a[1]); o.w[1] = cvtpk(a[2], a[3]);
        o.w[2] = cvtpk(b[0], b[1]); o.w[3] = cvtpk(b[2], b[3]);
        *(u16x8*)(dst + off) = o.v;
    }
}

// ---------------------------------------------------------------------------
// MEGA-1: blocks 0..511 = Q projection, 64x128 tile, 256 thr (R13-verified).
//         blocks 512..639 = precomp_M (256-thread version, R13-verified).
__global__ __launch_bounds__(256, 4) void k_mega1(
    const u16* __restrict__ xbf, const u16* __restrict__ Wqbf,
    const float* __restrict__ Wq, const float* __restrict__ Wv,
    const float* __restrict__ bq, const int* __restrict__ mask,
    u16* __restrict__ Qbf, u16* __restrict__ QT,
    float* __restrict__ sq05, float* __restrict__ Mpart) {
    __shared__ __align__(16) char smem[33792];
    const int tid = threadIdx.x;

    if (blockIdx.x >= 512) {
        // ---------------- precomp_M path (256 threads, 2x64-row chunks) -----
        const int id = blockIdx.x - 512;
        const int z = id & 7, h = id >> 3;
        float* Qp = (float*)smem;              // [64][64] f32 = 16384 B
        float* Vp = (float*)(smem + 16384);    // [64][64] f32 = 16384 B
        const int r = tid >> 2, seg = tid & 3;
        const int j0 = (tid >> 4) * 4;         // 16 groups x 4 j's = 64
        const int f0 = (tid & 15) * 4;         // 16 groups x 4 f's = 64
        f32x4 acc[4];
#pragma unroll
        for (int jj = 0; jj < 4; ++jj) acc[jj] = (f32x4){0.f, 0.f, 0.f, 0.f};
        for (int c = 0; c < 2; ++c) {
            const int e0 = z * 128 + c * 64;
            __syncthreads();
            const float* q = Wq + (size_t)(e0 + r) * D_DIM + h * DHEAD + seg * 16;
            const float* v = Wv + (size_t)(e0 + r) * D_DIM + h * DHEAD + seg * 16;
#pragma unroll
            for (int i = 0; i < 4; ++i) {
                *(f32x4*)&Qp[r * 64 + seg * 16 + i * 4] = *(const f32x4*)(q + i * 4);
                *(f32x4*)&Vp[r * 64 + seg * 16 + i * 4] = *(const f32x4*)(v + i * 4);
            }
            __syncthreads();
#pragma unroll 4
            for (int e = 0; e < 64; ++e) {
                f32x4 vv = *(const f32x4*)&Vp[e * 64 + f0];
#pragma unroll
                for (int jj = 0; jj < 4; ++jj)
                    acc[jj] += Qp[e * 64 + j0 + jj] * vv;
            }
        }
        float* dst = Mpart + (size_t)z * 65536 + ((size_t)(h * 64 + j0)) * 64 + f0;
#pragma unroll
        for (int jj = 0; jj < 4; ++jj)
            *(f32x4*)(dst + (size_t)jj * 64) = acc[jj] * 0.125f;
        return;
    }

    // ---------------- qproj path: 64 rows x 128 cols, 4 waves ----------------
    u16* Al = (u16*)smem;              // [64][72]  = 9216 B
    u16* Bl = (u16*)(smem + 9216);     // [128][72] = 18432 B
    float* sqp = (float*)(smem + 27648); // [4][64] f32 = 1024 B

    const int lane = tid & 63, wn = tid >> 6;   // wn 0..3 (32-col quarters)
    const int col16 = lane & 15, quad = lane >> 4;
    const int bm = blockIdx.x & 63, bn = blockIdx.x >> 6;

    f32x4 acc[4][2];
    const f32x4 z4 = {0.f, 0.f, 0.f, 0.f};
#pragma unroll
    for (int i = 0; i < 4; ++i)
#pragma unroll
        for (int j = 0; j < 2; ++j) acc[i][j] = z4;

    const int arA = tid >> 2, asA = tid & 3;
    const int brB = tid >> 1, bsB = tid & 1;
    const u16* pa = xbf + (size_t)(bm * 64 + arA) * D_DIM + asA * 16;
    const u16* pb = Wqbf + (size_t)(bn * 128 + brB) * D_DIM + bsB * 32;

    u16x8 ra[2], rb[4];
#pragma unroll
    for (int i = 0; i < 2; ++i) ra[i] = *(const u16x8*)(pa + i * 8);
#pragma unroll
    for (int i = 0; i < 4; ++i) rb[i] = *(const u16x8*)(pb + i * 8);

    for (int k0 = 0; k0 < D_DIM; k0 += 64) {
        __syncthreads();
#pragma unroll
        for (int i = 0; i < 2; ++i) *(u16x8*)&Al[arA * 72 + asA * 16 + i * 8] = ra[i];
#pragma unroll
        for (int i = 0; i < 4; ++i) *(u16x8*)&Bl[brB * 72 + bsB * 32 + i * 8] = rb[i];
        __syncthreads();
        if (k0 + 64 < D_DIM) {
#pragma unroll
            for (int i = 0; i < 2; ++i) ra[i] = *(const u16x8*)(pa + k0 + 64 + i * 8);
#pragma unroll
            for (int i = 0; i < 4; ++i) rb[i] = *(const u16x8*)(pb + k0 + 64 + i * 8);
        }
#pragma unroll
        for (int kh = 0; kh < 2; ++kh) {
            bf16x8 af[4];
#pragma unroll
            for (int mt = 0; mt < 4; ++mt)
                af[mt] = *(const bf16x8*)&Al[(mt * 16 + col16) * 72 + kh * 32 + quad * 8];
#pragma unroll
            for (int nt = 0; nt < 2; ++nt) {
                bf16x8 bfr = *(const bf16x8*)&Bl[(wn * 32 + nt * 16 + col16) * 72 + kh * 32 + quad * 8];
#pragma unroll
                for (int mt = 0; mt < 4; ++mt)
                    acc[mt][nt] = MFMA16(af[mt], bfr, acc[mt][nt]);
            }
        }
    }

    // epilogue: bias, Qbf store, ||q||^2 partials, LDS transpose for QT
    const int hh = wn >> 1;
    f32x4 ssum[4];
#pragma unroll
    for (int mt = 0; mt < 4; ++mt) ssum[mt] = z4;

    u16 qv16[2][4][4];
#pragma unroll
    for (int nt = 0; nt < 2; ++nt) {
        int col = bn * 128 + wn * 32 + nt * 16 + col16;
        float bqv = bq[col];
#pragma unroll
        for (int mt = 0; mt < 4; ++mt) {
            int row0 = bm * 64 + mt * 16 + quad * 4;
#pragma unroll
            for (int rr = 0; rr < 4; ++rr) {
                float qv = acc[mt][nt][rr] + bqv;
                ssum[mt][rr] += qv * qv;
                u16 bv = f2bf(qv);
                qv16[nt][mt][rr] = bv;
                Qbf[(size_t)(row0 + rr) * D_DIM + col] = bv;
            }
        }
    }
    float vred[4][4];
#pragma unroll
    for (int mt = 0; mt < 4; ++mt)
#pragma unroll
        for (int rr = 0; rr < 4; ++rr) {
            float v = ssum[mt][rr];
            v += __shfl_xor(v, 1); v += __shfl_xor(v, 2);
            v += __shfl_xor(v, 4); v += __shfl_xor(v, 8);
            vred[mt][rr] = v;
        }
    if (col16 == 0) {
#pragma unroll
        for (int mt = 0; mt < 4; ++mt)
#pragma unroll
            for (int rr = 0; rr < 4; ++rr)
                sqp[wn * 64 + mt * 16 + quad * 4 + rr] = vred[mt][rr];
    }
    __syncthreads();

    // transpose: Td[head_half][d][s_local], stride 66 u16 (64 + 2 pad)
    u16* Td = (u16*)smem;
#pragma unroll
    for (int nt = 0; nt < 2; ++nt) {
        int dloc = (wn & 1) * 32 + nt * 16 + col16;
#pragma unroll
        for (int mt = 0; mt < 4; ++mt) {
            int sl = mt * 16 + quad * 4;
#pragma unroll
            for (int rr = 0; rr < 4; ++rr)
                Td[(hh * 64 + dloc) * 66 + sl + rr] = qv16[nt][mt][rr];
        }
    }
    __syncthreads();

    const int bb = bm >> 5, s0 = (bm * 64) & 2047;
    if (tid < 128) {
        int r = tid & 63, hh2 = tid >> 6;
        float v = sqp[(2 * hh2) * 64 + r] + sqp[(2 * hh2 + 1) * 64 + r];
        int sidx = s0 + r;
        float o = mask[bb * S_LEN + sidx] ? v * C_SQ : 1e30f;
        sq05[((size_t)(bb * NH + bn * 2 + hh2)) * S_LEN + sidx] = o;
    }
    {
        int dr = tid >> 1, ch = tid & 1;
        int hh3 = dr >> 6, d = dr & 63;
        u16* dst = QT + ((size_t)(bb * NH + bn * 2 + hh3) * DHEAD + d) * S_LEN + s0 + ch * 32;
        const u16* src = Td + (hh3 * 64 + d) * 66 + ch * 32;
#pragma unroll
        for (int i = 0; i < 4; ++i)
            *(u16x8*)(dst + i * 8) = *(const u16x8*)(src + i * 8);
    }
}

// ---------------------------------------------------------------------------
// MEGA-2: blocks 0..255 = fused L2 attention, 2 q-tiles per block sharing one
//         staged K/V tile. 8 waves = sub(2 q-tiles) x wq(2) x wk(2); per-wave
//         compute = R9-verified code verbatim (qt = 2*(bid>>5) + sub).
//         blocks 256..511 = W2 fold (512-thread version).
__global__ __launch_bounds__(512, 2) void k_mega2(
    const u16* __restrict__ Qbf, const u16* __restrict__ QT,
    const float* __restrict__ sq05, u16* __restrict__ attnO,
    const float* __restrict__ Mpart, const float* __restrict__ Wout,
    u16* __restrict__ W2) {
    __shared__ __align__(16) char smem[34816];
    const int tid = threadIdx.x;

    if (blockIdx.x >= 256) {
        // ---------------- precomp_W2 path (512-thread) ----------------
        const int id = blockIdx.x - 256;
        const int ob = id & 15, h = id >> 4;
        float* Ms = (float*)smem;              // [64][65]
        float* Ws = (float*)(smem + 16640);    // [64][65]
        {
            int rr = tid >> 3, seg = tid & 7;
            const size_t mo = ((size_t)(h * 64 + rr)) * 64 + seg * 8;
            const float* ws = Wout + (size_t)(ob * 64 + rr) * D_DIM + h * DHEAD + seg * 8;
#pragma unroll
            for (int e = 0; e < 8; ++e) {
                float s = 0.f;
#pragma unroll
                for (int k = 0; k < 8; ++k) s += Mpart[mo + e + (size_t)k * 65536];
                Ms[rr * 65 + seg * 8 + e] = s;
                Ws[rr * 65 + seg * 8 + e] = ws[e];
            }
        }
        __syncthreads();
        int j = tid & 63, o0 = (tid >> 6) * 8;
        for (int oo = o0; oo < o0 + 8; ++oo) {
            float acc = 0.f;
#pragma unroll
            for (int f = 0; f < 64; ++f) acc += Ms[j * 65 + f] * Ws[oo * 65 + f];
            W2[(size_t)(ob * 64 + oo) * D_DIM + h * DHEAD + j] = f2bf(acc);
        }
        return;
    }

    // ---------------- flash path: 8 waves, 2 q-tiles, shared K/V ----------
    u16* Kt  = (u16*)smem;              // [128][64] u16, xor-swizzled cols
    u16* KtT = (u16*)(smem + 16384);    // [64][128] u16, xor-swizzled cols
    float* sql = (float*)(smem + 32768);// [128]

    const int lane = tid & 63, w = tid >> 6;
    const int col16 = lane & 15, quad = lane >> 4;
    const int wq = w & 1, wk = (w >> 1) & 1, sub = w >> 2;
    const int bh = blockIdx.x & 31;      // (b,h) in low bits -> same XCD
    const int qt = (blockIdx.x >> 5) * 2 + sub;   // 0..15, 128-row tiles
    const int h = bh & 15;
    const int b = bh >> 4;
    const u16* qbase = Qbf + (size_t)b * S_LEN * D_DIM + h * DHEAD;
    const u16* qtbase = QT + ((size_t)(b * NH + h)) * DHEAD * S_LEN;
    const float* sqb = sq05 + ((size_t)(b * NH + h)) * S_LEN;

    // loop-invariant Q^T B-fragments (global, once)
    bf16x8 qb[4][2];
#pragma unroll
    for (int nq = 0; nq < 4; ++nq)
#pragma unroll
        for (int k0 = 0; k0 < 2; ++k0)
            qb[nq][k0] = *(const bf16x8*)(qbase +
                (size_t)(qt * 128 + wq * 64 + nq * 16 + col16) * D_DIM + k0 * 32 + quad * 8);

    // Kt read offset closed form (R9-verified): krow = krow00 + kt*2048 + kbh*256
    const int r00 = wk * 64 + (col16 >> 2) * 8 + (col16 & 3);
    const int swzA = (col16 & 3) | (((col16 >> 2) & 1) << 2);
    const int krow00 = r00 * 64 + (quad ^ swzA) * 8;
    const int sq00 = wk * 64 + quad * 8;
    int vrow[4];
#pragma unroll
    for (int dblk = 0; dblk < 4; ++dblk) {
        int rT = dblk * 16 + col16;
        vrow[dblk] = rT * 128 + ((wk * 8 + quad) ^ (rT & 7)) * 8;
    }

    // staging assignments (512 threads, 2 chunks each; R11/R12-verified)
    const int kr = tid >> 2, ks = tid & 3;
    const int td = tid >> 3, ts = tid & 7;
    const int kswz = (kr & 3) | (((kr >> 3) & 1) << 2);
    const int tswz = td & 7;
    const u16* ksrc = qbase + (size_t)kr * D_DIM + ks * 16;
    const u16* tsrc = qtbase + (size_t)td * S_LEN + ts * 16;

    u16x8 pk[2], pt[2];
    float sv = 0.f;
#pragma unroll
    for (int i = 0; i < 2; ++i) pk[i] = *(const u16x8*)(ksrc + i * 8);
#pragma unroll
    for (int i = 0; i < 2; ++i) pt[i] = *(const u16x8*)(tsrc + i * 8);
    if (tid < 128) sv = sqb[tid];

    f32x4 Oacc[4][4], lacc[4];
    const f32x4 z4 = {0.f, 0.f, 0.f, 0.f};
#pragma unroll
    for (int n = 0; n < 4; ++n) {
        lacc[n] = z4;
#pragma unroll
        for (int d = 0; d < 4; ++d) Oacc[d][n] = z4;
    }
    bf16x8 ones;
    {
        union { u16x8 u; bf16x8 b; } cv;
#pragma unroll
        for (int e = 0; e < 8; ++e) cv.u[e] = 0x3F80;
        ones = cv.b;
    }

    for (int j = 0; j < S_LEN / 128; ++j) {
        __syncthreads();
#pragma unroll
        for (int i = 0; i < 2; ++i)
            *(u16x8*)(Kt + kr * 64 + ((ks * 2 + i) ^ kswz) * 8) = pk[i];
#pragma unroll
        for (int i = 0; i < 2; ++i)
            *(u16x8*)(KtT + td * 128 + ((ts * 2 + i) ^ tswz) * 8) = pt[i];
        if (tid < 128) sql[tid] = sv;
        __syncthreads();

        int jn = (j + 1) & 15;
        {
            const u16* kn = ksrc + (size_t)jn * 128 * D_DIM;
            const u16* tn = tsrc + (size_t)jn * 128;
#pragma unroll
            for (int i = 0; i < 2; ++i) pk[i] = *(const u16x8*)(kn + i * 8);
#pragma unroll
            for (int i = 0; i < 2; ++i) pt[i] = *(const u16x8*)(tn + i * 8);
            if (tid < 128) sv = sqb[jn * 128 + tid];
        }

        // two key-half rounds: S^T (32 keys x 64 q) -> exp/pack -> PV
        for (int kt = 0; kt < 2; ++kt) {
            f32x4 sacc[2][4];
#pragma unroll
            for (int kbh = 0; kbh < 2; ++kbh)
#pragma unroll
                for (int nq = 0; nq < 4; ++nq) sacc[kbh][nq] = z4;
#pragma unroll
            for (int kbh = 0; kbh < 2; ++kbh) {
                int kro = krow00 + kt * 2048 + kbh * 256;
                bf16x8 a0 = *(const bf16x8*)(Kt + kro);
                bf16x8 a1 = *(const bf16x8*)(Kt + (kro ^ 32));
#pragma unroll
                for (int nq = 0; nq < 4; ++nq) {
                    sacc[kbh][nq] = MFMA16(a0, qb[nq][0], sacc[kbh][nq]);
                    sacc[kbh][nq] = MFMA16(a1, qb[nq][1], sacc[kbh][nq]);
                }
            }

            // hoist V-fragment LDS reads: latency hides under the exp chain
            bf16x8 va[4];
#pragma unroll
            for (int dblk = 0; dblk < 4; ++dblk)
                va[dblk] = *(const bf16x8*)(KtT + (vrow[dblk] ^ (kt * 32)));

            u32 pf[4][4];
#pragma unroll
            for (int kbh = 0; kbh < 2; ++kbh) {
                f32x4 sqv = *(const f32x4*)(sql + sq00 + kt * 32 + kbh * 4);
#pragma unroll
                for (int nq = 0; nq < 4; ++nq) {
                    float p0 = EXP2(fmaf(sacc[kbh][nq][0], C_QK, -sqv[0]));
                    float p1 = EXP2(fmaf(sacc[kbh][nq][1], C_QK, -sqv[1]));
                    float p2 = EXP2(fmaf(sacc[kbh][nq][2], C_QK, -sqv[2]));
                    float p3 = EXP2(fmaf(sacc[kbh][nq][3], C_QK, -sqv[3]));
                    pf[nq][kbh * 2]     = pack_bf(p0, p1);
                    pf[nq][kbh * 2 + 1] = pack_bf(p2, p3);
                }
            }

#pragma unroll
            for (int nq = 0; nq < 4; ++nq) {
                union { u32 u[4]; bf16x8 b; } pb;
#pragma unroll
                for (int i = 0; i < 4; ++i) pb.u[i] = pf[nq][i];
                lacc[nq] = MFMA16(ones, pb.b, lacc[nq]);   // key-sums, rows replicated
#pragma unroll
                for (int dblk = 0; dblk < 4; ++dblk)
                    Oacc[dblk][nq] = MFMA16(va[dblk], pb.b, Oacc[dblk][nq]);
            }
        }
    }

    // cross-wave (key-half) combine + epilogue: R9 epilogue per sub-tile,
    // serialized through the shared Obuf (uniform barriers).
    __syncthreads();
    float* Obuf = (float*)smem;                 // [2][16][64] f32x4 = 32 KB
    float* lred = (float*)(smem + 32768);       // [2][4][64]
    u16* obase = attnO + (size_t)b * S_LEN * D_DIM + h * DHEAD;
    for (int s = 0; s < 2; ++s) {
        if (sub == s && wk == 1) {
#pragma unroll
            for (int dblk = 0; dblk < 4; ++dblk)
#pragma unroll
                for (int nq = 0; nq < 4; ++nq)
                    *(f32x4*)(Obuf + ((wq * 16 + dblk * 4 + nq) * 64 + lane) * 4) = Oacc[dblk][nq];
#pragma unroll
            for (int nq = 0; nq < 4; ++nq)
                lred[(wq * 4 + nq) * 64 + lane] = lacc[nq][0];
        }
        __syncthreads();
        if (sub == s && wk == 0) {
            float rinv[4];
#pragma unroll
            for (int nq = 0; nq < 4; ++nq)
                rinv[nq] = 1.f / (lacc[nq][0] + lred[(wq * 4 + nq) * 64 + lane]);
#pragma unroll
            for (int dblk = 0; dblk < 4; ++dblk)
#pragma unroll
                for (int nq = 0; nq < 4; ++nq) {
                    f32x4 o = Oacc[dblk][nq] + *(const f32x4*)(Obuf + ((wq * 16 + dblk * 4 + nq) * 64 + lane) * 4);
                    int q = qt * 128 + wq * 64 + nq * 16 + col16;
                    u16x4 pkk;
#pragma unroll
                    for (int rr = 0; rr < 4; ++rr) pkk[rr] = f2bf(o[rr] * rinv[nq]);
                    *(u16x4*)(obase + (size_t)q * D_DIM + dblk * 16 + quad * 4) = pkk;
                }
        }
        __syncthreads();
    }
}

// ---------------------------------------------------------------------------
// Output GEMM, 64x128 tile, 256 threads, grid (64,8) = 512 blocks (2/CU):
// out[s,o] = x[s,o] + bout[o] + attnO·W2^T
__global__ __launch_bounds__(256, 4) void k_oproj(
    const u16* __restrict__ attnO, const u16* __restrict__ W2,
    const float* __restrict__ x, const float* __restrict__ bout, float* __restrict__ out) {
    __shared__ __align__(16) char smem[27648];
    u16* Al = (u16*)smem;              // [64][72]
    u16* Bl = (u16*)(smem + 9216);     // [128][72]
    const int tid = threadIdx.x, lane = tid & 63, wn = tid >> 6;  // wn 0..3
    const int col16 = lane & 15, quad = lane >> 4;
    const int bm = blockIdx.x, bn = blockIdx.y;

    f32x4 acc[4][2];
    const f32x4 z4 = {0.f, 0.f, 0.f, 0.f};
#pragma unroll
    for (int i = 0; i < 4; ++i)
#pragma unroll
        for (int j = 0; j < 2; ++j) acc[i][j] = z4;

    const int arA = tid >> 2, asA = tid & 3;
    const int brB = tid >> 1, bsB = tid & 1;
    const u16* pa = attnO + (size_t)(bm * 64 + arA) * D_DIM + asA * 16;
    const u16* pb = W2 + (size_t)(bn * 128 + brB) * D_DIM + bsB * 32;

    u16x8 ra[2], rb[4];
#pragma unroll
    for (int i = 0; i < 2; ++i) ra[i] = *(const u16x8*)(pa + i * 8);
#pragma unroll
    for (int i = 0; i < 4; ++i) rb[i] = *(const u16x8*)(pb + i * 8);

    for (int k0 = 0; k0 < D_DIM; k0 += 64) {
        __syncthreads();
#pragma unroll
        for (int i = 0; i < 2; ++i) *(u16x8*)&Al[arA * 72 + asA * 16 + i * 8] = ra[i];
#pragma unroll
        for (int i = 0; i < 4; ++i) *(u16x8*)&Bl[brB * 72 + bsB * 32 + i * 8] = rb[i];
        __syncthreads();
        if (k0 + 64 < D_DIM) {
#pragma unroll
            for (int i = 0; i < 2; ++i) ra[i] = *(const u16x8*)(pa + k0 + 64 + i * 8);
#pragma unroll
            for (int i = 0; i < 4; ++i) rb[i] = *(const u16x8*)(pb + k0 + 64 + i * 8);
        }
#pragma unroll
        for (int kh = 0; kh < 2; ++kh) {
            bf16x8 af[4];
#pragma unroll
            for (int mt = 0; mt < 4; ++mt)
                af[mt] = *(const bf16x8*)&Al[(mt * 16 + col16) * 72 + kh * 32 + quad * 8];
#pragma unroll
            for (int nt = 0; nt < 2; ++nt) {
                bf16x8 bfr = *(const bf16x8*)&Bl[(wn * 32 + nt * 16 + col16) * 72 + kh * 32 + quad * 8];
#pragma unroll
                for (int mt = 0; mt < 4; ++mt)
                    acc[mt][nt] = MFMA16(af[mt], bfr, acc[mt][nt]);
            }
        }
    }
#pragma unroll
    for (int nt = 0; nt < 2; ++nt) {
        int col = bn * 128 + wn * 32 + nt * 16 + col16;
        float bv = bout[col];
#pragma unroll
        for (int mt = 0; mt < 4; ++mt) {
            int row0 = bm * 64 + mt * 16 + quad * 4;
#pragma unroll
            for (int rr = 0; rr < 4; ++rr) {
                size_t idx = (size_t)(row0 + rr) * D_DIM + col;
                out[idx] = acc[mt][nt][rr] + x[idx] + bv;
            }
        }
    }
}

// ---------------------------------------------------------------------------
extern "C" void kernel_launch(void* const* d_in, const int* in_sizes, int n_in,
                              void* d_out, int out_size, void* d_ws, size_t ws_size,
                              hipStream_t stream) {
    const float* x    = (const float*)d_in[0];
    const float* Wq   = (const float*)d_in[1];
    const float* bq   = (const float*)d_in[2];
    const float* Wv   = (const float*)d_in[3];
    const float* Wout = (const float*)d_in[4];
    const float* bout = (const float*)d_in[5];
    const int*   mask = (const int*)d_in[6];
    float* out = (float*)d_out;

    char* ws = (char*)d_ws;
    u16*   Qbf   = (u16*)(ws);                         // 8 MB
    u16*   QT    = (u16*)(ws + (8u << 20));            // 8 MB
    u16*   attnO = (u16*)(ws + (16u << 20));           // 8 MB (aliases xbf)
    u16*   W2    = (u16*)(ws + (24u << 20));           // 2 MB (aliases Wqbf)
    float* Mpart = (float*)(ws + (26u << 20));         // 2 MB (8 partials)
    float* sq05  = (float*)(ws + (28u << 20));         // 256 KB
    // bf16 operand staging: stream-ordered aliases (read before overwrite)
    u16*   xbf   = attnO;   // written by k_prep, read by k_mega1, then attnO
    u16*   Wqbf  = W2;      // written by k_prep, read by k_mega1, then W2

    k_prep<<<dim3(2048), dim3(256), 0, stream>>>(x, Wq, xbf, Wqbf);
    k_mega1<<<dim3(640), dim3(256), 0, stream>>>(xbf, Wqbf, Wq, Wv, bq, mask, Qbf, QT, sq05, Mpart);
    k_mega2<<<dim3(512), dim3(512), 0, stream>>>(Qbf, QT, sq05, attnO, Mpart, Wout, W2);
    k_oproj<<<dim3(64, 8), dim3(256), 0, stream>>>(attnO, W2, x, bout, out);
}